// Round 2
// baseline (3907.133 us; speedup 1.0000x reference)
//
#include <hip/hip_runtime.h>
#include <hip/hip_bf16.h>

#define BB 64
#define PP 100
#define NN 1000
#define EE 512
#define HH 8
#define KDD 64
#define MM 10
#define ROWS (BB*PP)          // 6400
#define K1K 1026              // 2E+2
#define INVSQE 0.044194173824159216f  // 1/sqrt(512)
#define CLIPV 10.0f

union F4 { float4 v; float f[4]; };

// ---------------------------------------------------------------- K0: row max of cur_dist
__global__ __launch_bounds__(256) void k_rowmax(const float* __restrict__ cd,
                                                float* __restrict__ rmax) {
  int row = blockIdx.x * 4 + (threadIdx.x >> 6);
  int lane = threadIdx.x & 63;
  const float* src = cd + (size_t)row * NN;
  float m = -1e30f;
  for (int i = lane; i < NN; i += 64) m = fmaxf(m, src[i]);
  #pragma unroll
  for (int off = 32; off; off >>= 1) m = fmaxf(m, __shfl_xor(m, off));
  if (lane == 0) rmax[row] = m;
}

// ---------------------------------------------------------------- K1: q = q_first + heads(X @ Wq^T) + heads(info @ dis_emb^T)
__global__ __launch_bounds__(256) void k_qgemm(
    const float* __restrict__ eln, const float* __restrict__ ela,
    const float* __restrict__ lengths, const float* __restrict__ max_dis,
    const float* __restrict__ remain, const float* __restrict__ q_first,
    const float* __restrict__ Wq, const float* __restrict__ dis_emb,
    const int* __restrict__ depot, const int* __restrict__ route_cnt,
    const int* __restrict__ left_city, const int* __restrict__ city_num,
    float* __restrict__ qout) {
  __shared__ float Xs[64][36];
  __shared__ float Ws[64][36];
  __shared__ float info_s[64][4];
  __shared__ float fl_s[64][2];
  const int t = threadIdx.x;
  const int rowBase = blockIdx.y * 64, colBase = blockIdx.x * 64;
  if (t < 64) {
    int row = rowBase + t;
    int b = row / PP;
    int rc = route_cnt[row];
    int rn = depot[b] - 1;
    info_s[t][0] = lengths[row * MM + rc];
    info_s[t][1] = lengths[row * MM + rn];
    info_s[t][2] = max_dis[row];
    info_s[t][3] = remain[row];
    fl_s[t][0] = 1.0f - (float)(rc + 1) / (float)(rn + 1);
    fl_s[t][1] = (float)left_city[row] / (float)city_num[0];
  }
  __syncthreads();
  float acc[4][4];
  #pragma unroll
  for (int i = 0; i < 4; ++i)
    #pragma unroll
    for (int j = 0; j < 4; ++j) acc[i][j] = 0.f;
  const int tx = t & 15, ty = t >> 4;
  for (int kt = 0; kt < 33; ++kt) {
    const int k0 = kt * 32;
    #pragma unroll
    for (int i = 0; i < 8; ++i) {
      int e = i * 256 + t;
      int r = e >> 5, c = e & 31;
      int j = k0 + c;
      int row = rowBase + r;
      float xv;
      if (j < 512)       xv = eln[(size_t)row * 512 + j];
      else if (j < 1024) xv = ela[(size_t)row * 512 + j - 512];
      else if (j == 1024) xv = fl_s[r][0];
      else if (j == 1025) xv = fl_s[r][1];
      else xv = 0.f;
      Xs[r][c] = xv;
      Ws[r][c] = (j < K1K) ? Wq[(size_t)(colBase + r) * K1K + j] : 0.f;
    }
    __syncthreads();
    #pragma unroll
    for (int kc = 0; kc < 32; kc += 4) {
      F4 xv[4], wv[4];
      #pragma unroll
      for (int i = 0; i < 4; ++i) xv[i].v = *(const float4*)&Xs[ty + 16 * i][kc];
      #pragma unroll
      for (int j = 0; j < 4; ++j) wv[j].v = *(const float4*)&Ws[tx + 16 * j][kc];
      #pragma unroll
      for (int c = 0; c < 4; ++c)
        #pragma unroll
        for (int i = 0; i < 4; ++i)
          #pragma unroll
          for (int j = 0; j < 4; ++j)
            acc[i][j] += xv[i].f[c] * wv[j].f[c];
    }
    __syncthreads();
  }
  #pragma unroll
  for (int i = 0; i < 4; ++i) {
    int r = ty + 16 * i;
    int row = rowBase + r;
    int b = row / PP, p = row % PP;
    F4 inf; inf.v = *(const float4*)&info_s[r][0];
    #pragma unroll
    for (int j = 0; j < 4; ++j) {
      int o = colBase + tx + 16 * j;
      F4 de; de.v = *(const float4*)&dis_emb[(size_t)o * 4];
      float v = acc[i][j]
              + inf.f[0] * de.f[0] + inf.f[1] * de.f[1]
              + inf.f[2] * de.f[2] + inf.f[3] * de.f[3]
              + q_first[(((size_t)b * HH + (o >> 6)) * PP + p) * KDD + (o & 63)];
      qout[(size_t)row * 512 + o] = v;
    }
  }
}

// ---------------------------------------------------------------- K2: masked MHA — flash-style, parallel softmax.
// One block per (b, h, p-half). 52 query rows/block, N chunks of 64.
// Thread (tx,ty): rows ty+16i (i<4), score cols tx+16j, PV d-cols tx*4..+3.
// All hot LDS accesses <=2-way bank aliasing (free).
__global__ __launch_bounds__(256, 2) void k_attn(
    const float* __restrict__ qin, const float* __restrict__ kk,
    const float* __restrict__ vv, const float* __restrict__ mask,
    float* __restrict__ attn_out) {
  __shared__ float q_s[64][68];
  __shared__ float k_s[64][68];
  __shared__ float v_s[64][68];
  __shared__ float S_s[64][68];
  const int t = threadIdx.x;
  const int tx = t & 15, ty = t >> 4;
  const int bh2 = blockIdx.x;
  const int half = bh2 & 1, bh = bh2 >> 1;
  const int b = bh >> 3, h = bh & 7;
  const int p0 = half * 52;

  // q tile (scaled by 1/8), rows >= 52 or p >= PP zero-padded
  for (int idx = t; idx < 64 * 16; idx += 256) {
    int r = idx >> 4, d4 = (idx & 15) * 4;
    float4 qv = make_float4(0.f, 0.f, 0.f, 0.f);
    int p = p0 + r;
    if (r < 52 && p < PP)
      qv = *(const float4*)&qin[((size_t)(b * PP + p)) * 512 + h * 64 + d4];
    qv.x *= 0.125f; qv.y *= 0.125f; qv.z *= 0.125f; qv.w *= 0.125f;
    *(float4*)&q_s[r][d4] = qv;
  }

  int rows[4];
  #pragma unroll
  for (int i = 0; i < 4; ++i) rows[i] = ty + 16 * i;

  float M[4], L[4], o[4][4];
  #pragma unroll
  for (int i = 0; i < 4; ++i) {
    M[i] = -1e30f; L[i] = 0.f;
    #pragma unroll
    for (int c = 0; c < 4; ++c) o[i][c] = 0.f;
  }

  for (int ch = 0; ch < 16; ++ch) {
    const int n0 = ch * 64;
    // stage k/v chunk
    for (int idx = t; idx < 64 * 16; idx += 256) {
      int r = idx >> 4, d4 = (idx & 15) * 4;
      int n = n0 + r;
      float4 kv = make_float4(0.f, 0.f, 0.f, 0.f), v4 = kv;
      if (n < NN) {
        size_t base = ((size_t)bh * NN + n) * 64 + d4;
        kv = *(const float4*)&kk[base];
        v4 = *(const float4*)&vv[base];
      }
      *(float4*)&k_s[r][d4] = kv;
      *(float4*)&v_s[r][d4] = v4;
    }
    __syncthreads();   // q_s (first iter) + k_s/v_s ready

    // phase A: scores for 4 rows x 4 cols
    float sacc[4][4];
    #pragma unroll
    for (int i = 0; i < 4; ++i)
      #pragma unroll
      for (int j = 0; j < 4; ++j) sacc[i][j] = 0.f;
    #pragma unroll
    for (int d4 = 0; d4 < 16; ++d4) {
      F4 qv[4], kv[4];
      #pragma unroll
      for (int i = 0; i < 4; ++i) qv[i].v = *(const float4*)&q_s[rows[i]][d4 * 4];
      #pragma unroll
      for (int j = 0; j < 4; ++j) kv[j].v = *(const float4*)&k_s[tx + 16 * j][d4 * 4];
      #pragma unroll
      for (int c = 0; c < 4; ++c)
        #pragma unroll
        for (int i = 0; i < 4; ++i)
          #pragma unroll
          for (int j = 0; j < 4; ++j)
            sacc[i][j] += qv[i].f[c] * kv[j].f[c];
    }

    // mask add + online softmax (all threads, shuffle row-reduce over 16 lanes)
    float rscale[4];
    #pragma unroll
    for (int i = 0; i < 4; ++i) {
      int p = p0 + rows[i];
      bool rowok = (rows[i] < 52) && (p < PP);
      const float* mrow = rowok ? &mask[((size_t)(b * PP + p)) * NN] : nullptr;
      #pragma unroll
      for (int j = 0; j < 4; ++j) {
        int n = n0 + tx + 16 * j;
        float s = -1e30f;
        if (n < NN) {
          s = sacc[i][j];
          if (rowok) s += mrow[n];
        }
        sacc[i][j] = s;
      }
      float cm = fmaxf(fmaxf(sacc[i][0], sacc[i][1]), fmaxf(sacc[i][2], sacc[i][3]));
      #pragma unroll
      for (int off = 1; off < 16; off <<= 1) cm = fmaxf(cm, __shfl_xor(cm, off));
      float Mn = fmaxf(M[i], cm);
      float r = __expf(M[i] - Mn);
      float sum = 0.f;
      #pragma unroll
      for (int j = 0; j < 4; ++j) {
        float e = __expf(sacc[i][j] - Mn);
        S_s[rows[i]][tx + 16 * j] = e;
        sum += e;
      }
      #pragma unroll
      for (int off = 1; off < 16; off <<= 1) sum += __shfl_xor(sum, off);
      L[i] = L[i] * r + sum;
      M[i] = Mn;
      rscale[i] = r;
    }
    __syncthreads();   // S_s ready

    // phase B: o = o*r + S @ V  (d-slice tx*4..+3)
    #pragma unroll
    for (int i = 0; i < 4; ++i)
      #pragma unroll
      for (int c = 0; c < 4; ++c) o[i][c] *= rscale[i];
    #pragma unroll
    for (int n4 = 0; n4 < 16; ++n4) {
      F4 w[4], vx[4];
      #pragma unroll
      for (int i = 0; i < 4; ++i) w[i].v = *(const float4*)&S_s[rows[i]][n4 * 4];
      #pragma unroll
      for (int kkx = 0; kkx < 4; ++kkx) vx[kkx].v = *(const float4*)&v_s[n4 * 4 + kkx][tx * 4];
      #pragma unroll
      for (int i = 0; i < 4; ++i)
        #pragma unroll
        for (int kkx = 0; kkx < 4; ++kkx)
          #pragma unroll
          for (int c = 0; c < 4; ++c)
            o[i][c] += w[i].f[kkx] * vx[kkx].f[c];
    }
    __syncthreads();   // protect k_s/v_s/S_s before next stage
  }

  // epilogue
  #pragma unroll
  for (int i = 0; i < 4; ++i) {
    int r = rows[i], p = p0 + r;
    if (r < 52 && p < PP) {
      float inv = (L[i] > 0.f) ? 1.0f / L[i] : 0.f;
      float4 ov = make_float4(o[i][0] * inv, o[i][1] * inv, o[i][2] * inv, o[i][3] * inv);
      *(float4*)&attn_out[((size_t)(b * PP + p)) * 512 + h * 64 + tx * 4] = ov;
    }
  }
}

// ---------------------------------------------------------------- K3: mh = attn_out @ mh_w^T + mh_b
__global__ __launch_bounds__(256) void k_mhgemm(
    const float* __restrict__ A, const float* __restrict__ W,
    const float* __restrict__ bias, float* __restrict__ out) {
  __shared__ float Xs[64][36];
  __shared__ float Ws[64][36];
  const int t = threadIdx.x;
  const int rowBase = blockIdx.y * 64, colBase = blockIdx.x * 64;
  const int tx = t & 15, ty = t >> 4;
  float acc[4][4];
  #pragma unroll
  for (int i = 0; i < 4; ++i)
    #pragma unroll
    for (int j = 0; j < 4; ++j) acc[i][j] = 0.f;
  for (int kt = 0; kt < 16; ++kt) {
    const int k0 = kt * 32;
    #pragma unroll
    for (int i = 0; i < 8; ++i) {
      int e = i * 256 + t;
      int r = e >> 5, c = e & 31;
      Xs[r][c] = A[(size_t)(rowBase + r) * 512 + k0 + c];
      Ws[r][c] = W[(size_t)(colBase + r) * 512 + k0 + c];
    }
    __syncthreads();
    #pragma unroll
    for (int kc = 0; kc < 32; kc += 4) {
      F4 xv[4], wv[4];
      #pragma unroll
      for (int i = 0; i < 4; ++i) xv[i].v = *(const float4*)&Xs[ty + 16 * i][kc];
      #pragma unroll
      for (int j = 0; j < 4; ++j) wv[j].v = *(const float4*)&Ws[tx + 16 * j][kc];
      #pragma unroll
      for (int c = 0; c < 4; ++c)
        #pragma unroll
        for (int i = 0; i < 4; ++i)
          #pragma unroll
          for (int j = 0; j < 4; ++j)
            acc[i][j] += xv[i].f[c] * wv[j].f[c];
    }
    __syncthreads();
  }
  #pragma unroll
  for (int i = 0; i < 4; ++i) {
    int row = rowBase + ty + 16 * i;
    #pragma unroll
    for (int j = 0; j < 4; ++j) {
      int o = colBase + tx + 16 * j;
      out[(size_t)row * 512 + o] = acc[i][j] + bias[o];
    }
  }
}

// ---------------------------------------------------------------- K4a: score2 = mh @ shk, then 10*tanh(s/sqrtE - a*cd/cdmax) + mask
__global__ __launch_bounds__(256) void k_final_score(
    const float* __restrict__ mh, const float* __restrict__ shk,
    const float* __restrict__ cur_dist, const float* __restrict__ rmax,
    const float* __restrict__ mask, const float* __restrict__ dist_alpha,
    float* __restrict__ sc_out) {
  __shared__ float mh_s[16][36];
  __shared__ float shk_s[32][260];
  const int t = threadIdx.x;
  const int b = blockIdx.z, p0 = blockIdx.y * 16, n0 = blockIdx.x * 256;
  const int pg = t >> 6, ng = t & 63;
  float acc[4][4];
  #pragma unroll
  for (int i = 0; i < 4; ++i)
    #pragma unroll
    for (int j = 0; j < 4; ++j) acc[i][j] = 0.f;
  for (int kt = 0; kt < 16; ++kt) {
    const int k0 = kt * 32;
    if (t < 128) {
      int r = t >> 3, c4 = (t & 7) * 4;
      float4 mv = make_float4(0.f, 0.f, 0.f, 0.f);
      if (p0 + r < PP) mv = *(const float4*)&mh[((size_t)(b * PP + p0 + r)) * 512 + k0 + c4];
      *(float4*)&mh_s[r][c4] = mv;
    }
    #pragma unroll
    for (int i = 0; i < 8; ++i) {
      int idx = i * 256 + t;
      int e = idx >> 6, n4 = (idx & 63) * 4;
      int n = n0 + n4;
      const float* src = &shk[((size_t)(b * 512 + k0 + e)) * NN + n];
      float4 sv = make_float4(0.f, 0.f, 0.f, 0.f);
      if (n + 3 < NN) sv = *(const float4*)src;
      else if (n < NN) {
        sv.x = src[0];
        if (n + 1 < NN) sv.y = src[1];
        if (n + 2 < NN) sv.z = src[2];
      }
      *(float4*)&shk_s[e][n4] = sv;
    }
    __syncthreads();
    #pragma unroll
    for (int k = 0; k < 32; k += 4) {
      F4 a0, a1, a2, a3;
      a0.v = *(const float4*)&mh_s[pg * 4 + 0][k];
      a1.v = *(const float4*)&mh_s[pg * 4 + 1][k];
      a2.v = *(const float4*)&mh_s[pg * 4 + 2][k];
      a3.v = *(const float4*)&mh_s[pg * 4 + 3][k];
      #pragma unroll
      for (int kk = 0; kk < 4; ++kk) {
        F4 bv; bv.v = *(const float4*)&shk_s[k + kk][ng * 4];
        #pragma unroll
        for (int c = 0; c < 4; ++c) {
          acc[0][c] += a0.f[kk] * bv.f[c];
          acc[1][c] += a1.f[kk] * bv.f[c];
          acc[2][c] += a2.f[kk] * bv.f[c];
          acc[3][c] += a3.f[kk] * bv.f[c];
        }
      }
    }
    __syncthreads();
  }
  const float alpha = dist_alpha[0];
  #pragma unroll
  for (int i = 0; i < 4; ++i) {
    int p = p0 + pg * 4 + i;
    if (p >= PP) continue;
    size_t rb = (size_t)(b * PP + p) * NN;
    float rmx = rmax[b * PP + p];
    int n = n0 + ng * 4;
    if (n >= NN) continue;
    if (n + 3 < NN) {
      F4 cd, mk, o;
      cd.v = *(const float4*)&cur_dist[rb + n];
      mk.v = *(const float4*)&mask[rb + n];
      #pragma unroll
      for (int j = 0; j < 4; ++j)
        o.f[j] = CLIPV * tanhf(acc[i][j] * INVSQE - alpha * cd.f[j] / rmx) + mk.f[j];
      *(float4*)&sc_out[rb + n] = o.v;
    } else {
      #pragma unroll
      for (int j = 0; j < 4; ++j) {
        if (n + j < NN) {
          float cd = cur_dist[rb + n + j];
          float mk = mask[rb + n + j];
          sc_out[rb + n + j] = CLIPV * tanhf(acc[i][j] * INVSQE - alpha * cd / rmx) + mk;
        }
      }
    }
  }
}

// ---------------------------------------------------------------- K4b: row softmax over N
__global__ __launch_bounds__(256) void k_softmax(const float* __restrict__ sc,
                                                 float* __restrict__ out) {
  __shared__ float redm[4];
  __shared__ float redsum[4];
  const int row = blockIdx.x;
  const int t = threadIdx.x;
  const float* src = sc + (size_t)row * NN;
  float v0[4];
  float m = -1e30f;
  #pragma unroll
  for (int i = 0; i < 4; ++i) {
    int n = i * 256 + t;
    v0[i] = (n < NN) ? src[n] : -1e30f;
    m = fmaxf(m, v0[i]);
  }
  #pragma unroll
  for (int off = 32; off; off >>= 1) m = fmaxf(m, __shfl_xor(m, off));
  int wid = t >> 6, lane = t & 63;
  if (lane == 0) redm[wid] = m;
  __syncthreads();
  m = fmaxf(fmaxf(redm[0], redm[1]), fmaxf(redm[2], redm[3]));
  float e[4];
  float s = 0.f;
  #pragma unroll
  for (int i = 0; i < 4; ++i) {
    int n = i * 256 + t;
    e[i] = (n < NN) ? __expf(v0[i] - m) : 0.f;
    s += e[i];
  }
  #pragma unroll
  for (int off = 32; off; off >>= 1) s += __shfl_xor(s, off);
  if (lane == 0) redsum[wid] = s;
  __syncthreads();
  s = redsum[0] + redsum[1] + redsum[2] + redsum[3];
  float inv = 1.0f / s;
  #pragma unroll
  for (int i = 0; i < 4; ++i) {
    int n = i * 256 + t;
    if (n < NN) out[(size_t)row * NN + n] = e[i] * inv;
  }
}

// ----------------------------------------------------------------
extern "C" void kernel_launch(void* const* d_in, const int* in_sizes, int n_in,
                              void* d_out, int out_size, void* d_ws, size_t ws_size,
                              hipStream_t stream) {
  const float* eln       = (const float*)d_in[0];
  const float* ela       = (const float*)d_in[1];
  const float* cur_dist  = (const float*)d_in[2];
  const float* ninf      = (const float*)d_in[3];
  const float* lengths   = (const float*)d_in[4];
  const float* max_dis   = (const float*)d_in[5];
  const float* remain    = (const float*)d_in[6];
  const float* q_first   = (const float*)d_in[7];
  const float* kten      = (const float*)d_in[8];
  const float* vten      = (const float*)d_in[9];
  const float* shk       = (const float*)d_in[10];
  const float* Wq        = (const float*)d_in[11];
  const float* dis_emb   = (const float*)d_in[12];
  const float* mh_w      = (const float*)d_in[13];
  const float* mh_b      = (const float*)d_in[14];
  const float* dalpha    = (const float*)d_in[15];
  const int*   depot     = (const int*)d_in[16];
  const int*   route_cnt = (const int*)d_in[17];
  const int*   left_city = (const int*)d_in[18];
  const int*   city_num  = (const int*)d_in[19];
  float* out = (float*)d_out;

  float* ws      = (float*)d_ws;
  float* q_ws    = ws;                                   // 6400*512
  float* attn_ws = q_ws + (size_t)ROWS * 512;            // 6400*512
  float* mh_ws   = attn_ws + (size_t)ROWS * 512;         // 6400*512
  float* sc_ws   = mh_ws + (size_t)ROWS * 512;           // 6400*1000
  float* rmax_ws = sc_ws + (size_t)ROWS * NN;            // 6400

  k_rowmax<<<ROWS / 4, 256, 0, stream>>>(cur_dist, rmax_ws);
  k_qgemm<<<dim3(8, 100), 256, 0, stream>>>(eln, ela, lengths, max_dis, remain,
                                            q_first, Wq, dis_emb, depot, route_cnt,
                                            left_city, city_num, q_ws);
  k_attn<<<BB * HH * 2, 256, 0, stream>>>(q_ws, kten, vten, ninf, attn_ws);
  k_mhgemm<<<dim3(8, 100), 256, 0, stream>>>(attn_ws, mh_w, mh_b, mh_ws);
  k_final_score<<<dim3(4, 7, 64), 256, 0, stream>>>(mh_ws, shk, cur_dist, rmax_ws,
                                                    ninf, dalpha, sc_ws);
  k_softmax<<<ROWS, 256, 0, stream>>>(sc_ws, out);
}

// Round 3
// 1912.065 us; speedup vs baseline: 2.0434x; 2.0434x over previous
//
#include <hip/hip_runtime.h>
#include <hip/hip_bf16.h>

#define BB 64
#define PP 100
#define NN 1000
#define EE 512
#define HH 8
#define KDD 64
#define MM 10
#define ROWS (BB*PP)          // 6400
#define K1K 1026              // 2E+2
#define INVSQE 0.044194173824159216f  // 1/sqrt(512)
#define CLIPV 10.0f

union F4 { float4 v; float f[4]; };

// ---------------------------------------------------------------- K0: row max of cur_dist
__global__ __launch_bounds__(256) void k_rowmax(const float* __restrict__ cd,
                                                float* __restrict__ rmax) {
  int row = blockIdx.x * 4 + (threadIdx.x >> 6);
  int lane = threadIdx.x & 63;
  const float* src = cd + (size_t)row * NN;
  float m = -1e30f;
  for (int i = lane; i < NN; i += 64) m = fmaxf(m, src[i]);
  #pragma unroll
  for (int off = 32; off; off >>= 1) m = fmaxf(m, __shfl_xor(m, off));
  if (lane == 0) rmax[row] = m;
}

// ---------------------------------------------------------------- K1: q = q_first + heads(X @ Wq^T) + heads(info @ dis_emb^T)
__global__ __launch_bounds__(256) void k_qgemm(
    const float* __restrict__ eln, const float* __restrict__ ela,
    const float* __restrict__ lengths, const float* __restrict__ max_dis,
    const float* __restrict__ remain, const float* __restrict__ q_first,
    const float* __restrict__ Wq, const float* __restrict__ dis_emb,
    const int* __restrict__ depot, const int* __restrict__ route_cnt,
    const int* __restrict__ left_city, const int* __restrict__ city_num,
    float* __restrict__ qout) {
  __shared__ float Xs[64][36];
  __shared__ float Ws[64][36];
  __shared__ float info_s[64][4];
  __shared__ float fl_s[64][2];
  const int t = threadIdx.x;
  const int rowBase = blockIdx.y * 64, colBase = blockIdx.x * 64;
  if (t < 64) {
    int row = rowBase + t;
    int b = row / PP;
    int rc = route_cnt[row];
    int rn = depot[b] - 1;
    info_s[t][0] = lengths[row * MM + rc];
    info_s[t][1] = lengths[row * MM + rn];
    info_s[t][2] = max_dis[row];
    info_s[t][3] = remain[row];
    fl_s[t][0] = 1.0f - (float)(rc + 1) / (float)(rn + 1);
    fl_s[t][1] = (float)left_city[row] / (float)city_num[0];
  }
  __syncthreads();
  float acc[4][4];
  #pragma unroll
  for (int i = 0; i < 4; ++i)
    #pragma unroll
    for (int j = 0; j < 4; ++j) acc[i][j] = 0.f;
  const int tx = t & 15, ty = t >> 4;
  for (int kt = 0; kt < 33; ++kt) {
    const int k0 = kt * 32;
    #pragma unroll
    for (int i = 0; i < 8; ++i) {
      int e = i * 256 + t;
      int r = e >> 5, c = e & 31;
      int j = k0 + c;
      int row = rowBase + r;
      float xv;
      if (j < 512)       xv = eln[(size_t)row * 512 + j];
      else if (j < 1024) xv = ela[(size_t)row * 512 + j - 512];
      else if (j == 1024) xv = fl_s[r][0];
      else if (j == 1025) xv = fl_s[r][1];
      else xv = 0.f;
      Xs[r][c] = xv;
      Ws[r][c] = (j < K1K) ? Wq[(size_t)(colBase + r) * K1K + j] : 0.f;
    }
    __syncthreads();
    #pragma unroll
    for (int kc = 0; kc < 32; kc += 4) {
      F4 xv[4], wv[4];
      #pragma unroll
      for (int i = 0; i < 4; ++i) xv[i].v = *(const float4*)&Xs[ty + 16 * i][kc];
      #pragma unroll
      for (int j = 0; j < 4; ++j) wv[j].v = *(const float4*)&Ws[tx + 16 * j][kc];
      #pragma unroll
      for (int c = 0; c < 4; ++c)
        #pragma unroll
        for (int i = 0; i < 4; ++i)
          #pragma unroll
          for (int j = 0; j < 4; ++j)
            acc[i][j] += xv[i].f[c] * wv[j].f[c];
    }
    __syncthreads();
  }
  #pragma unroll
  for (int i = 0; i < 4; ++i) {
    int r = ty + 16 * i;
    int row = rowBase + r;
    int b = row / PP, p = row % PP;
    F4 inf; inf.v = *(const float4*)&info_s[r][0];
    #pragma unroll
    for (int j = 0; j < 4; ++j) {
      int o = colBase + tx + 16 * j;
      F4 de; de.v = *(const float4*)&dis_emb[(size_t)o * 4];
      float v = acc[i][j]
              + inf.f[0] * de.f[0] + inf.f[1] * de.f[1]
              + inf.f[2] * de.f[2] + inf.f[3] * de.f[3]
              + q_first[(((size_t)b * HH + (o >> 6)) * PP + p) * KDD + (o & 63)];
      qout[(size_t)row * 512 + o] = v;
    }
  }
}

// ---------------------------------------------------------------- K2: masked MHA — flash-style, parallel softmax.
// One block per (b, h, p-half). 52 query rows/block, N chunks of 64.
// NOTE: no min-waves arg in launch_bounds — a ",2" here capped VGPR at 128
// and caused a 7 GB scratch-spill storm (round 2). LDS caps occupancy anyway.
__global__ __launch_bounds__(256) void k_attn(
    const float* __restrict__ qin, const float* __restrict__ kk,
    const float* __restrict__ vv, const float* __restrict__ mask,
    float* __restrict__ attn_out) {
  __shared__ float q_s[64][68];
  __shared__ float k_s[64][68];
  __shared__ float v_s[64][68];
  __shared__ float S_s[64][68];
  const int t = threadIdx.x;
  const int tx = t & 15, ty = t >> 4;
  const int bh2 = blockIdx.x;
  const int half = bh2 & 1, bh = bh2 >> 1;
  const int b = bh >> 3, h = bh & 7;
  const int p0 = half * 52;

  // q tile (scaled by 1/8), rows >= 52 or p >= PP zero-padded
  for (int idx = t; idx < 64 * 16; idx += 256) {
    int r = idx >> 4, d4 = (idx & 15) * 4;
    float4 qv = make_float4(0.f, 0.f, 0.f, 0.f);
    int p = p0 + r;
    if (r < 52 && p < PP)
      qv = *(const float4*)&qin[((size_t)(b * PP + p)) * 512 + h * 64 + d4];
    qv.x *= 0.125f; qv.y *= 0.125f; qv.z *= 0.125f; qv.w *= 0.125f;
    *(float4*)&q_s[r][d4] = qv;
  }

  int rows[4];
  #pragma unroll
  for (int i = 0; i < 4; ++i) rows[i] = ty + 16 * i;

  float M[4], L[4], o[4][4];
  #pragma unroll
  for (int i = 0; i < 4; ++i) {
    M[i] = -1e30f; L[i] = 0.f;
    #pragma unroll
    for (int c = 0; c < 4; ++c) o[i][c] = 0.f;
  }

  for (int ch = 0; ch < 16; ++ch) {
    const int n0 = ch * 64;
    // stage k/v chunk
    for (int idx = t; idx < 64 * 16; idx += 256) {
      int r = idx >> 4, d4 = (idx & 15) * 4;
      int n = n0 + r;
      float4 kv = make_float4(0.f, 0.f, 0.f, 0.f), v4 = kv;
      if (n < NN) {
        size_t base = ((size_t)bh * NN + n) * 64 + d4;
        kv = *(const float4*)&kk[base];
        v4 = *(const float4*)&vv[base];
      }
      *(float4*)&k_s[r][d4] = kv;
      *(float4*)&v_s[r][d4] = v4;
    }
    __syncthreads();   // q_s (first iter) + k_s/v_s ready

    // phase A: scores for 4 rows x 4 cols
    float sacc[4][4];
    #pragma unroll
    for (int i = 0; i < 4; ++i)
      #pragma unroll
      for (int j = 0; j < 4; ++j) sacc[i][j] = 0.f;
    #pragma unroll
    for (int d4 = 0; d4 < 16; ++d4) {
      F4 qv[4], kv[4];
      #pragma unroll
      for (int i = 0; i < 4; ++i) qv[i].v = *(const float4*)&q_s[rows[i]][d4 * 4];
      #pragma unroll
      for (int j = 0; j < 4; ++j) kv[j].v = *(const float4*)&k_s[tx + 16 * j][d4 * 4];
      #pragma unroll
      for (int c = 0; c < 4; ++c)
        #pragma unroll
        for (int i = 0; i < 4; ++i)
          #pragma unroll
          for (int j = 0; j < 4; ++j)
            sacc[i][j] += qv[i].f[c] * kv[j].f[c];
    }

    // mask add + online softmax (all threads, shuffle row-reduce over 16 lanes)
    float rscale[4];
    #pragma unroll
    for (int i = 0; i < 4; ++i) {
      int p = p0 + rows[i];
      bool rowok = (rows[i] < 52) && (p < PP);
      const float* mrow = rowok ? &mask[((size_t)(b * PP + p)) * NN] : nullptr;
      #pragma unroll
      for (int j = 0; j < 4; ++j) {
        int n = n0 + tx + 16 * j;
        float s = -1e30f;
        if (n < NN) {
          s = sacc[i][j];
          if (rowok) s += mrow[n];
        }
        sacc[i][j] = s;
      }
      float cm = fmaxf(fmaxf(sacc[i][0], sacc[i][1]), fmaxf(sacc[i][2], sacc[i][3]));
      #pragma unroll
      for (int off = 1; off < 16; off <<= 1) cm = fmaxf(cm, __shfl_xor(cm, off));
      float Mn = fmaxf(M[i], cm);
      float r = __expf(M[i] - Mn);
      float sum = 0.f;
      #pragma unroll
      for (int j = 0; j < 4; ++j) {
        float e = __expf(sacc[i][j] - Mn);
        S_s[rows[i]][tx + 16 * j] = e;
        sum += e;
      }
      #pragma unroll
      for (int off = 1; off < 16; off <<= 1) sum += __shfl_xor(sum, off);
      L[i] = L[i] * r + sum;
      M[i] = Mn;
      rscale[i] = r;
    }
    __syncthreads();   // S_s ready

    // phase B: o = o*r + S @ V  (d-slice tx*4..+3)
    #pragma unroll
    for (int i = 0; i < 4; ++i)
      #pragma unroll
      for (int c = 0; c < 4; ++c) o[i][c] *= rscale[i];
    #pragma unroll
    for (int n4 = 0; n4 < 16; ++n4) {
      F4 w[4], vx[4];
      #pragma unroll
      for (int i = 0; i < 4; ++i) w[i].v = *(const float4*)&S_s[rows[i]][n4 * 4];
      #pragma unroll
      for (int kkx = 0; kkx < 4; ++kkx) vx[kkx].v = *(const float4*)&v_s[n4 * 4 + kkx][tx * 4];
      #pragma unroll
      for (int i = 0; i < 4; ++i)
        #pragma unroll
        for (int kkx = 0; kkx < 4; ++kkx)
          #pragma unroll
          for (int c = 0; c < 4; ++c)
            o[i][c] += w[i].f[kkx] * vx[kkx].f[c];
    }
    __syncthreads();   // protect k_s/v_s/S_s before next stage
  }

  // epilogue
  #pragma unroll
  for (int i = 0; i < 4; ++i) {
    int r = rows[i], p = p0 + r;
    if (r < 52 && p < PP) {
      float inv = (L[i] > 0.f) ? 1.0f / L[i] : 0.f;
      float4 ov = make_float4(o[i][0] * inv, o[i][1] * inv, o[i][2] * inv, o[i][3] * inv);
      *(float4*)&attn_out[((size_t)(b * PP + p)) * 512 + h * 64 + tx * 4] = ov;
    }
  }
}

// ---------------------------------------------------------------- K3: mh = attn_out @ mh_w^T + mh_b
__global__ __launch_bounds__(256) void k_mhgemm(
    const float* __restrict__ A, const float* __restrict__ W,
    const float* __restrict__ bias, float* __restrict__ out) {
  __shared__ float Xs[64][36];
  __shared__ float Ws[64][36];
  const int t = threadIdx.x;
  const int rowBase = blockIdx.y * 64, colBase = blockIdx.x * 64;
  const int tx = t & 15, ty = t >> 4;
  float acc[4][4];
  #pragma unroll
  for (int i = 0; i < 4; ++i)
    #pragma unroll
    for (int j = 0; j < 4; ++j) acc[i][j] = 0.f;
  for (int kt = 0; kt < 16; ++kt) {
    const int k0 = kt * 32;
    #pragma unroll
    for (int i = 0; i < 8; ++i) {
      int e = i * 256 + t;
      int r = e >> 5, c = e & 31;
      Xs[r][c] = A[(size_t)(rowBase + r) * 512 + k0 + c];
      Ws[r][c] = W[(size_t)(colBase + r) * 512 + k0 + c];
    }
    __syncthreads();
    #pragma unroll
    for (int kc = 0; kc < 32; kc += 4) {
      F4 xv[4], wv[4];
      #pragma unroll
      for (int i = 0; i < 4; ++i) xv[i].v = *(const float4*)&Xs[ty + 16 * i][kc];
      #pragma unroll
      for (int j = 0; j < 4; ++j) wv[j].v = *(const float4*)&Ws[tx + 16 * j][kc];
      #pragma unroll
      for (int c = 0; c < 4; ++c)
        #pragma unroll
        for (int i = 0; i < 4; ++i)
          #pragma unroll
          for (int j = 0; j < 4; ++j)
            acc[i][j] += xv[i].f[c] * wv[j].f[c];
    }
    __syncthreads();
  }
  #pragma unroll
  for (int i = 0; i < 4; ++i) {
    int row = rowBase + ty + 16 * i;
    #pragma unroll
    for (int j = 0; j < 4; ++j) {
      int o = colBase + tx + 16 * j;
      out[(size_t)row * 512 + o] = acc[i][j] + bias[o];
    }
  }
}

// ---------------------------------------------------------------- K4a: score2 = mh @ shk, then 10*tanh(s/sqrtE - a*cd/cdmax) + mask
__global__ __launch_bounds__(256) void k_final_score(
    const float* __restrict__ mh, const float* __restrict__ shk,
    const float* __restrict__ cur_dist, const float* __restrict__ rmax,
    const float* __restrict__ mask, const float* __restrict__ dist_alpha,
    float* __restrict__ sc_out) {
  __shared__ float mh_s[16][36];
  __shared__ float shk_s[32][260];
  const int t = threadIdx.x;
  const int b = blockIdx.z, p0 = blockIdx.y * 16, n0 = blockIdx.x * 256;
  const int pg = t >> 6, ng = t & 63;
  float acc[4][4];
  #pragma unroll
  for (int i = 0; i < 4; ++i)
    #pragma unroll
    for (int j = 0; j < 4; ++j) acc[i][j] = 0.f;
  for (int kt = 0; kt < 16; ++kt) {
    const int k0 = kt * 32;
    if (t < 128) {
      int r = t >> 3, c4 = (t & 7) * 4;
      float4 mv = make_float4(0.f, 0.f, 0.f, 0.f);
      if (p0 + r < PP) mv = *(const float4*)&mh[((size_t)(b * PP + p0 + r)) * 512 + k0 + c4];
      *(float4*)&mh_s[r][c4] = mv;
    }
    #pragma unroll
    for (int i = 0; i < 8; ++i) {
      int idx = i * 256 + t;
      int e = idx >> 6, n4 = (idx & 63) * 4;
      int n = n0 + n4;
      const float* src = &shk[((size_t)(b * 512 + k0 + e)) * NN + n];
      float4 sv = make_float4(0.f, 0.f, 0.f, 0.f);
      if (n + 3 < NN) sv = *(const float4*)src;
      else if (n < NN) {
        sv.x = src[0];
        if (n + 1 < NN) sv.y = src[1];
        if (n + 2 < NN) sv.z = src[2];
      }
      *(float4*)&shk_s[e][n4] = sv;
    }
    __syncthreads();
    #pragma unroll
    for (int k = 0; k < 32; k += 4) {
      F4 a0, a1, a2, a3;
      a0.v = *(const float4*)&mh_s[pg * 4 + 0][k];
      a1.v = *(const float4*)&mh_s[pg * 4 + 1][k];
      a2.v = *(const float4*)&mh_s[pg * 4 + 2][k];
      a3.v = *(const float4*)&mh_s[pg * 4 + 3][k];
      #pragma unroll
      for (int kk = 0; kk < 4; ++kk) {
        F4 bv; bv.v = *(const float4*)&shk_s[k + kk][ng * 4];
        #pragma unroll
        for (int c = 0; c < 4; ++c) {
          acc[0][c] += a0.f[kk] * bv.f[c];
          acc[1][c] += a1.f[kk] * bv.f[c];
          acc[2][c] += a2.f[kk] * bv.f[c];
          acc[3][c] += a3.f[kk] * bv.f[c];
        }
      }
    }
    __syncthreads();
  }
  const float alpha = dist_alpha[0];
  #pragma unroll
  for (int i = 0; i < 4; ++i) {
    int p = p0 + pg * 4 + i;
    if (p >= PP) continue;
    size_t rb = (size_t)(b * PP + p) * NN;
    float rmx = rmax[b * PP + p];
    int n = n0 + ng * 4;
    if (n >= NN) continue;
    if (n + 3 < NN) {
      F4 cd, mk, o;
      cd.v = *(const float4*)&cur_dist[rb + n];
      mk.v = *(const float4*)&mask[rb + n];
      #pragma unroll
      for (int j = 0; j < 4; ++j)
        o.f[j] = CLIPV * tanhf(acc[i][j] * INVSQE - alpha * cd.f[j] / rmx) + mk.f[j];
      *(float4*)&sc_out[rb + n] = o.v;
    } else {
      #pragma unroll
      for (int j = 0; j < 4; ++j) {
        if (n + j < NN) {
          float cd = cur_dist[rb + n + j];
          float mk = mask[rb + n + j];
          sc_out[rb + n + j] = CLIPV * tanhf(acc[i][j] * INVSQE - alpha * cd / rmx) + mk;
        }
      }
    }
  }
}

// ---------------------------------------------------------------- K4b: row softmax over N
__global__ __launch_bounds__(256) void k_softmax(const float* __restrict__ sc,
                                                 float* __restrict__ out) {
  __shared__ float redm[4];
  __shared__ float redsum[4];
  const int row = blockIdx.x;
  const int t = threadIdx.x;
  const float* src = sc + (size_t)row * NN;
  float v0[4];
  float m = -1e30f;
  #pragma unroll
  for (int i = 0; i < 4; ++i) {
    int n = i * 256 + t;
    v0[i] = (n < NN) ? src[n] : -1e30f;
    m = fmaxf(m, v0[i]);
  }
  #pragma unroll
  for (int off = 32; off; off >>= 1) m = fmaxf(m, __shfl_xor(m, off));
  int wid = t >> 6, lane = t & 63;
  if (lane == 0) redm[wid] = m;
  __syncthreads();
  m = fmaxf(fmaxf(redm[0], redm[1]), fmaxf(redm[2], redm[3]));
  float e[4];
  float s = 0.f;
  #pragma unroll
  for (int i = 0; i < 4; ++i) {
    int n = i * 256 + t;
    e[i] = (n < NN) ? __expf(v0[i] - m) : 0.f;
    s += e[i];
  }
  #pragma unroll
  for (int off = 32; off; off >>= 1) s += __shfl_xor(s, off);
  if (lane == 0) redsum[wid] = s;
  __syncthreads();
  s = redsum[0] + redsum[1] + redsum[2] + redsum[3];
  float inv = 1.0f / s;
  #pragma unroll
  for (int i = 0; i < 4; ++i) {
    int n = i * 256 + t;
    if (n < NN) out[(size_t)row * NN + n] = e[i] * inv;
  }
}

// ----------------------------------------------------------------
extern "C" void kernel_launch(void* const* d_in, const int* in_sizes, int n_in,
                              void* d_out, int out_size, void* d_ws, size_t ws_size,
                              hipStream_t stream) {
  const float* eln       = (const float*)d_in[0];
  const float* ela       = (const float*)d_in[1];
  const float* cur_dist  = (const float*)d_in[2];
  const float* ninf      = (const float*)d_in[3];
  const float* lengths   = (const float*)d_in[4];
  const float* max_dis   = (const float*)d_in[5];
  const float* remain    = (const float*)d_in[6];
  const float* q_first   = (const float*)d_in[7];
  const float* kten      = (const float*)d_in[8];
  const float* vten      = (const float*)d_in[9];
  const float* shk       = (const float*)d_in[10];
  const float* Wq        = (const float*)d_in[11];
  const float* dis_emb   = (const float*)d_in[12];
  const float* mh_w      = (const float*)d_in[13];
  const float* mh_b      = (const float*)d_in[14];
  const float* dalpha    = (const float*)d_in[15];
  const int*   depot     = (const int*)d_in[16];
  const int*   route_cnt = (const int*)d_in[17];
  const int*   left_city = (const int*)d_in[18];
  const int*   city_num  = (const int*)d_in[19];
  float* out = (float*)d_out;

  float* ws      = (float*)d_ws;
  float* q_ws    = ws;                                   // 6400*512
  float* attn_ws = q_ws + (size_t)ROWS * 512;            // 6400*512
  float* mh_ws   = attn_ws + (size_t)ROWS * 512;         // 6400*512
  float* sc_ws   = mh_ws + (size_t)ROWS * 512;           // 6400*1000
  float* rmax_ws = sc_ws + (size_t)ROWS * NN;            // 6400

  k_rowmax<<<ROWS / 4, 256, 0, stream>>>(cur_dist, rmax_ws);
  k_qgemm<<<dim3(8, 100), 256, 0, stream>>>(eln, ela, lengths, max_dis, remain,
                                            q_first, Wq, dis_emb, depot, route_cnt,
                                            left_city, city_num, q_ws);
  k_attn<<<BB * HH * 2, 256, 0, stream>>>(q_ws, kten, vten, ninf, attn_ws);
  k_mhgemm<<<dim3(8, 100), 256, 0, stream>>>(attn_ws, mh_w, mh_b, mh_ws);
  k_final_score<<<dim3(4, 7, 64), 256, 0, stream>>>(mh_ws, shk, cur_dist, rmax_ws,
                                                    ninf, dalpha, sc_ws);
  k_softmax<<<ROWS, 256, 0, stream>>>(sc_ws, out);
}

// Round 4
// 1035.299 us; speedup vs baseline: 3.7739x; 1.8469x over previous
//
#include <hip/hip_runtime.h>
#include <hip/hip_bf16.h>

#define BB 64
#define PP 100
#define NN 1000
#define EE 512
#define HH 8
#define KDD 64
#define MM 10
#define ROWS (BB*PP)          // 6400
#define K1K 1026              // 2E+2
#define INVSQE 0.044194173824159216f  // 1/sqrt(512)
#define CLIPV 10.0f

union F4 { float4 v; float f[4]; };

// ---------------------------------------------------------------- K0: row max of cur_dist
__global__ __launch_bounds__(256) void k_rowmax(const float* __restrict__ cd,
                                                float* __restrict__ rmax) {
  int row = blockIdx.x * 4 + (threadIdx.x >> 6);
  int lane = threadIdx.x & 63;
  const float* src = cd + (size_t)row * NN;
  float m = -1e30f;
  for (int i = lane; i < NN; i += 64) m = fmaxf(m, src[i]);
  #pragma unroll
  for (int off = 32; off; off >>= 1) m = fmaxf(m, __shfl_xor(m, off));
  if (lane == 0) rmax[row] = m;
}

// ---------------------------------------------------------------- K1: q = q_first + heads(X @ Wq^T) + heads(info @ dis_emb^T)
__global__ __launch_bounds__(256) void k_qgemm(
    const float* __restrict__ eln, const float* __restrict__ ela,
    const float* __restrict__ lengths, const float* __restrict__ max_dis,
    const float* __restrict__ remain, const float* __restrict__ q_first,
    const float* __restrict__ Wq, const float* __restrict__ dis_emb,
    const int* __restrict__ depot, const int* __restrict__ route_cnt,
    const int* __restrict__ left_city, const int* __restrict__ city_num,
    float* __restrict__ qout) {
  __shared__ float Xs[64][36];
  __shared__ float Ws[64][36];
  __shared__ float info_s[64][4];
  __shared__ float fl_s[64][2];
  const int t = threadIdx.x;
  const int rowBase = blockIdx.y * 64, colBase = blockIdx.x * 64;
  if (t < 64) {
    int row = rowBase + t;
    int b = row / PP;
    int rc = route_cnt[row];
    int rn = depot[b] - 1;
    info_s[t][0] = lengths[row * MM + rc];
    info_s[t][1] = lengths[row * MM + rn];
    info_s[t][2] = max_dis[row];
    info_s[t][3] = remain[row];
    fl_s[t][0] = 1.0f - (float)(rc + 1) / (float)(rn + 1);
    fl_s[t][1] = (float)left_city[row] / (float)city_num[0];
  }
  __syncthreads();
  float acc[4][4];
  #pragma unroll
  for (int i = 0; i < 4; ++i)
    #pragma unroll
    for (int j = 0; j < 4; ++j) acc[i][j] = 0.f;
  const int tx = t & 15, ty = t >> 4;
  for (int kt = 0; kt < 33; ++kt) {
    const int k0 = kt * 32;
    #pragma unroll
    for (int i = 0; i < 8; ++i) {
      int e = i * 256 + t;
      int r = e >> 5, c = e & 31;
      int j = k0 + c;
      int row = rowBase + r;
      float xv;
      if (j < 512)       xv = eln[(size_t)row * 512 + j];
      else if (j < 1024) xv = ela[(size_t)row * 512 + j - 512];
      else if (j == 1024) xv = fl_s[r][0];
      else if (j == 1025) xv = fl_s[r][1];
      else xv = 0.f;
      Xs[r][c] = xv;
      Ws[r][c] = (j < K1K) ? Wq[(size_t)(colBase + r) * K1K + j] : 0.f;
    }
    __syncthreads();
    #pragma unroll
    for (int kc = 0; kc < 32; kc += 4) {
      F4 xv[4], wv[4];
      #pragma unroll
      for (int i = 0; i < 4; ++i) xv[i].v = *(const float4*)&Xs[ty + 16 * i][kc];
      #pragma unroll
      for (int j = 0; j < 4; ++j) wv[j].v = *(const float4*)&Ws[tx + 16 * j][kc];
      #pragma unroll
      for (int c = 0; c < 4; ++c)
        #pragma unroll
        for (int i = 0; i < 4; ++i)
          #pragma unroll
          for (int j = 0; j < 4; ++j)
            acc[i][j] += xv[i].f[c] * wv[j].f[c];
    }
    __syncthreads();
  }
  #pragma unroll
  for (int i = 0; i < 4; ++i) {
    int r = ty + 16 * i;
    int row = rowBase + r;
    int b = row / PP, p = row % PP;
    F4 inf; inf.v = *(const float4*)&info_s[r][0];
    #pragma unroll
    for (int j = 0; j < 4; ++j) {
      int o = colBase + tx + 16 * j;
      F4 de; de.v = *(const float4*)&dis_emb[(size_t)o * 4];
      float v = acc[i][j]
              + inf.f[0] * de.f[0] + inf.f[1] * de.f[1]
              + inf.f[2] * de.f[2] + inf.f[3] * de.f[3]
              + q_first[(((size_t)b * HH + (o >> 6)) * PP + p) * KDD + (o & 63)];
      qout[(size_t)row * 512 + o] = v;
    }
  }
}

// ---------------------------------------------------------------- K2: masked MHA — flash-style, parallel softmax.
// One block per (b, h, p-half). 52 query rows/block, N chunks of 64.
// LESSONS ENCODED HERE:
//  - no min-waves arg in launch_bounds: ",2" capped VGPR at 128 -> 7 GB
//    scratch storm (round 2).
//  - mask is staged into LDS (reusing S_s) during k/v staging: per-thread
//    global mask loads inside the main loop got hoisted above the unrolled
//    FMA wall and spilled ~660 MB/dispatch even at 256 VGPRs (round 3).
//    Each thread reads mask at exactly the S_s cells it later overwrites
//    with exp values -> no race, no extra barrier.
__global__ __launch_bounds__(256) void k_attn(
    const float* __restrict__ qin, const float* __restrict__ kk,
    const float* __restrict__ vv, const float* __restrict__ mask,
    float* __restrict__ attn_out) {
  __shared__ float q_s[64][68];
  __shared__ float k_s[64][68];
  __shared__ float v_s[64][68];
  __shared__ float S_s[64][68];   // mask chunk before softmax, exp(S) after
  const int t = threadIdx.x;
  const int tx = t & 15, ty = t >> 4;
  const int bh2 = blockIdx.x;
  const int half = bh2 & 1, bh = bh2 >> 1;
  const int b = bh >> 3, h = bh & 7;
  const int p0 = half * 52;

  // q tile (scaled by 1/8), rows >= 52 or p >= PP zero-padded
  for (int idx = t; idx < 64 * 16; idx += 256) {
    int r = idx >> 4, d4 = (idx & 15) * 4;
    float4 qv = make_float4(0.f, 0.f, 0.f, 0.f);
    int p = p0 + r;
    if (r < 52 && p < PP)
      qv = *(const float4*)&qin[((size_t)(b * PP + p)) * 512 + h * 64 + d4];
    qv.x *= 0.125f; qv.y *= 0.125f; qv.z *= 0.125f; qv.w *= 0.125f;
    *(float4*)&q_s[r][d4] = qv;
  }

  int rows[4];
  #pragma unroll
  for (int i = 0; i < 4; ++i) rows[i] = ty + 16 * i;

  float M[4], L[4], o[4][4];
  #pragma unroll
  for (int i = 0; i < 4; ++i) {
    M[i] = -1e30f; L[i] = 0.f;
    #pragma unroll
    for (int c = 0; c < 4; ++c) o[i][c] = 0.f;
  }

  for (int ch = 0; ch < 16; ++ch) {
    const int n0 = ch * 64;
    // stage k/v chunk + mask chunk (mask goes into S_s; coalesced 16B rows)
    for (int idx = t; idx < 64 * 16; idx += 256) {
      int r = idx >> 4, d4 = (idx & 15) * 4;
      int n = n0 + r;
      float4 kv = make_float4(0.f, 0.f, 0.f, 0.f), v4 = kv;
      if (n < NN) {
        size_t base = ((size_t)bh * NN + n) * 64 + d4;
        kv = *(const float4*)&kk[base];
        v4 = *(const float4*)&vv[base];
      }
      *(float4*)&k_s[r][d4] = kv;
      *(float4*)&v_s[r][d4] = v4;
      // mask: query row r, key cols n0+d4 .. n0+d4+3
      float4 mv = make_float4(0.f, 0.f, 0.f, 0.f);
      int p = p0 + r;
      int nm = n0 + d4;
      if (r < 52 && p < PP) {
        const float* msrc = &mask[((size_t)(b * PP + p)) * NN + nm];
        if (nm + 3 < NN) mv = *(const float4*)msrc;
        else {
          if (nm     < NN) mv.x = msrc[0];
          if (nm + 1 < NN) mv.y = msrc[1];
          if (nm + 2 < NN) mv.z = msrc[2];
        }
      }
      *(float4*)&S_s[r][d4] = mv;
    }
    __syncthreads();   // k_s/v_s/S_s(mask) ready

    // phase A: scores for 4 rows x 4 cols
    float sacc[4][4];
    #pragma unroll
    for (int i = 0; i < 4; ++i)
      #pragma unroll
      for (int j = 0; j < 4; ++j) sacc[i][j] = 0.f;
    #pragma unroll
    for (int d4 = 0; d4 < 16; ++d4) {
      F4 qv[4], kv[4];
      #pragma unroll
      for (int i = 0; i < 4; ++i) qv[i].v = *(const float4*)&q_s[rows[i]][d4 * 4];
      #pragma unroll
      for (int j = 0; j < 4; ++j) kv[j].v = *(const float4*)&k_s[tx + 16 * j][d4 * 4];
      #pragma unroll
      for (int c = 0; c < 4; ++c)
        #pragma unroll
        for (int i = 0; i < 4; ++i)
          #pragma unroll
          for (int j = 0; j < 4; ++j)
            sacc[i][j] += qv[i].f[c] * kv[j].f[c];
    }

    // mask add (from LDS, own cells) + online softmax (shuffle row-reduce)
    float rscale[4];
    #pragma unroll
    for (int i = 0; i < 4; ++i) {
      #pragma unroll
      for (int j = 0; j < 4; ++j) {
        int n = n0 + tx + 16 * j;
        float s = sacc[i][j] + S_s[rows[i]][tx + 16 * j];
        sacc[i][j] = (n < NN) ? s : -1e30f;
      }
      float cm = fmaxf(fmaxf(sacc[i][0], sacc[i][1]), fmaxf(sacc[i][2], sacc[i][3]));
      #pragma unroll
      for (int off = 1; off < 16; off <<= 1) cm = fmaxf(cm, __shfl_xor(cm, off));
      float Mn = fmaxf(M[i], cm);
      float r = __expf(M[i] - Mn);
      float sum = 0.f;
      #pragma unroll
      for (int j = 0; j < 4; ++j) {
        float e = __expf(sacc[i][j] - Mn);
        S_s[rows[i]][tx + 16 * j] = e;   // overwrite own mask cells
        sum += e;
      }
      #pragma unroll
      for (int off = 1; off < 16; off <<= 1) sum += __shfl_xor(sum, off);
      L[i] = L[i] * r + sum;
      M[i] = Mn;
      rscale[i] = r;
    }
    __syncthreads();   // S_s now exp-weights, visible to all

    // phase B: o = o*r + S @ V  (d-slice tx*4..+3)
    #pragma unroll
    for (int i = 0; i < 4; ++i)
      #pragma unroll
      for (int c = 0; c < 4; ++c) o[i][c] *= rscale[i];
    #pragma unroll
    for (int n4 = 0; n4 < 16; ++n4) {
      F4 w[4], vx[4];
      #pragma unroll
      for (int i = 0; i < 4; ++i) w[i].v = *(const float4*)&S_s[rows[i]][n4 * 4];
      #pragma unroll
      for (int kkx = 0; kkx < 4; ++kkx) vx[kkx].v = *(const float4*)&v_s[n4 * 4 + kkx][tx * 4];
      #pragma unroll
      for (int i = 0; i < 4; ++i)
        #pragma unroll
        for (int kkx = 0; kkx < 4; ++kkx)
          #pragma unroll
          for (int c = 0; c < 4; ++c)
            o[i][c] += w[i].f[kkx] * vx[kkx].f[c];
    }
    __syncthreads();   // protect k_s/v_s/S_s before next stage
  }

  // epilogue
  #pragma unroll
  for (int i = 0; i < 4; ++i) {
    int r = rows[i], p = p0 + r;
    if (r < 52 && p < PP) {
      float inv = (L[i] > 0.f) ? 1.0f / L[i] : 0.f;
      float4 ov = make_float4(o[i][0] * inv, o[i][1] * inv, o[i][2] * inv, o[i][3] * inv);
      *(float4*)&attn_out[((size_t)(b * PP + p)) * 512 + h * 64 + tx * 4] = ov;
    }
  }
}

// ---------------------------------------------------------------- K3: mh = attn_out @ mh_w^T + mh_b
__global__ __launch_bounds__(256) void k_mhgemm(
    const float* __restrict__ A, const float* __restrict__ W,
    const float* __restrict__ bias, float* __restrict__ out) {
  __shared__ float Xs[64][36];
  __shared__ float Ws[64][36];
  const int t = threadIdx.x;
  const int rowBase = blockIdx.y * 64, colBase = blockIdx.x * 64;
  const int tx = t & 15, ty = t >> 4;
  float acc[4][4];
  #pragma unroll
  for (int i = 0; i < 4; ++i)
    #pragma unroll
    for (int j = 0; j < 4; ++j) acc[i][j] = 0.f;
  for (int kt = 0; kt < 16; ++kt) {
    const int k0 = kt * 32;
    #pragma unroll
    for (int i = 0; i < 8; ++i) {
      int e = i * 256 + t;
      int r = e >> 5, c = e & 31;
      Xs[r][c] = A[(size_t)(rowBase + r) * 512 + k0 + c];
      Ws[r][c] = W[(size_t)(colBase + r) * 512 + k0 + c];
    }
    __syncthreads();
    #pragma unroll
    for (int kc = 0; kc < 32; kc += 4) {
      F4 xv[4], wv[4];
      #pragma unroll
      for (int i = 0; i < 4; ++i) xv[i].v = *(const float4*)&Xs[ty + 16 * i][kc];
      #pragma unroll
      for (int j = 0; j < 4; ++j) wv[j].v = *(const float4*)&Ws[tx + 16 * j][kc];
      #pragma unroll
      for (int c = 0; c < 4; ++c)
        #pragma unroll
        for (int i = 0; i < 4; ++i)
          #pragma unroll
          for (int j = 0; j < 4; ++j)
            acc[i][j] += xv[i].f[c] * wv[j].f[c];
    }
    __syncthreads();
  }
  #pragma unroll
  for (int i = 0; i < 4; ++i) {
    int row = rowBase + ty + 16 * i;
    #pragma unroll
    for (int j = 0; j < 4; ++j) {
      int o = colBase + tx + 16 * j;
      out[(size_t)row * 512 + o] = acc[i][j] + bias[o];
    }
  }
}

// ---------------------------------------------------------------- K4a: score2 = mh @ shk, then 10*tanh(s/sqrtE - a*cd/cdmax) + mask
__global__ __launch_bounds__(256) void k_final_score(
    const float* __restrict__ mh, const float* __restrict__ shk,
    const float* __restrict__ cur_dist, const float* __restrict__ rmax,
    const float* __restrict__ mask, const float* __restrict__ dist_alpha,
    float* __restrict__ sc_out) {
  __shared__ float mh_s[16][36];
  __shared__ float shk_s[32][260];
  const int t = threadIdx.x;
  const int b = blockIdx.z, p0 = blockIdx.y * 16, n0 = blockIdx.x * 256;
  const int pg = t >> 6, ng = t & 63;
  float acc[4][4];
  #pragma unroll
  for (int i = 0; i < 4; ++i)
    #pragma unroll
    for (int j = 0; j < 4; ++j) acc[i][j] = 0.f;
  for (int kt = 0; kt < 16; ++kt) {
    const int k0 = kt * 32;
    if (t < 128) {
      int r = t >> 3, c4 = (t & 7) * 4;
      float4 mv = make_float4(0.f, 0.f, 0.f, 0.f);
      if (p0 + r < PP) mv = *(const float4*)&mh[((size_t)(b * PP + p0 + r)) * 512 + k0 + c4];
      *(float4*)&mh_s[r][c4] = mv;
    }
    #pragma unroll
    for (int i = 0; i < 8; ++i) {
      int idx = i * 256 + t;
      int e = idx >> 6, n4 = (idx & 63) * 4;
      int n = n0 + n4;
      const float* src = &shk[((size_t)(b * 512 + k0 + e)) * NN + n];
      float4 sv = make_float4(0.f, 0.f, 0.f, 0.f);
      if (n + 3 < NN) sv = *(const float4*)src;
      else if (n < NN) {
        sv.x = src[0];
        if (n + 1 < NN) sv.y = src[1];
        if (n + 2 < NN) sv.z = src[2];
      }
      *(float4*)&shk_s[e][n4] = sv;
    }
    __syncthreads();
    #pragma unroll
    for (int k = 0; k < 32; k += 4) {
      F4 a0, a1, a2, a3;
      a0.v = *(const float4*)&mh_s[pg * 4 + 0][k];
      a1.v = *(const float4*)&mh_s[pg * 4 + 1][k];
      a2.v = *(const float4*)&mh_s[pg * 4 + 2][k];
      a3.v = *(const float4*)&mh_s[pg * 4 + 3][k];
      #pragma unroll
      for (int kk = 0; kk < 4; ++kk) {
        F4 bv; bv.v = *(const float4*)&shk_s[k + kk][ng * 4];
        #pragma unroll
        for (int c = 0; c < 4; ++c) {
          acc[0][c] += a0.f[kk] * bv.f[c];
          acc[1][c] += a1.f[kk] * bv.f[c];
          acc[2][c] += a2.f[kk] * bv.f[c];
          acc[3][c] += a3.f[kk] * bv.f[c];
        }
      }
    }
    __syncthreads();
  }
  const float alpha = dist_alpha[0];
  #pragma unroll
  for (int i = 0; i < 4; ++i) {
    int p = p0 + pg * 4 + i;
    if (p >= PP) continue;
    size_t rb = (size_t)(b * PP + p) * NN;
    float rmx = rmax[b * PP + p];
    int n = n0 + ng * 4;
    if (n >= NN) continue;
    if (n + 3 < NN) {
      F4 cd, mk, o;
      cd.v = *(const float4*)&cur_dist[rb + n];
      mk.v = *(const float4*)&mask[rb + n];
      #pragma unroll
      for (int j = 0; j < 4; ++j)
        o.f[j] = CLIPV * tanhf(acc[i][j] * INVSQE - alpha * cd.f[j] / rmx) + mk.f[j];
      *(float4*)&sc_out[rb + n] = o.v;
    } else {
      #pragma unroll
      for (int j = 0; j < 4; ++j) {
        if (n + j < NN) {
          float cd = cur_dist[rb + n + j];
          float mk = mask[rb + n + j];
          sc_out[rb + n + j] = CLIPV * tanhf(acc[i][j] * INVSQE - alpha * cd / rmx) + mk;
        }
      }
    }
  }
}

// ---------------------------------------------------------------- K4b: row softmax over N
__global__ __launch_bounds__(256) void k_softmax(const float* __restrict__ sc,
                                                 float* __restrict__ out) {
  __shared__ float redm[4];
  __shared__ float redsum[4];
  const int row = blockIdx.x;
  const int t = threadIdx.x;
  const float* src = sc + (size_t)row * NN;
  float v0[4];
  float m = -1e30f;
  #pragma unroll
  for (int i = 0; i < 4; ++i) {
    int n = i * 256 + t;
    v0[i] = (n < NN) ? src[n] : -1e30f;
    m = fmaxf(m, v0[i]);
  }
  #pragma unroll
  for (int off = 32; off; off >>= 1) m = fmaxf(m, __shfl_xor(m, off));
  int wid = t >> 6, lane = t & 63;
  if (lane == 0) redm[wid] = m;
  __syncthreads();
  m = fmaxf(fmaxf(redm[0], redm[1]), fmaxf(redm[2], redm[3]));
  float e[4];
  float s = 0.f;
  #pragma unroll
  for (int i = 0; i < 4; ++i) {
    int n = i * 256 + t;
    e[i] = (n < NN) ? __expf(v0[i] - m) : 0.f;
    s += e[i];
  }
  #pragma unroll
  for (int off = 32; off; off >>= 1) s += __shfl_xor(s, off);
  if (lane == 0) redsum[wid] = s;
  __syncthreads();
  s = redsum[0] + redsum[1] + redsum[2] + redsum[3];
  float inv = 1.0f / s;
  #pragma unroll
  for (int i = 0; i < 4; ++i) {
    int n = i * 256 + t;
    if (n < NN) out[(size_t)row * NN + n] = e[i] * inv;
  }
}

// ----------------------------------------------------------------
extern "C" void kernel_launch(void* const* d_in, const int* in_sizes, int n_in,
                              void* d_out, int out_size, void* d_ws, size_t ws_size,
                              hipStream_t stream) {
  const float* eln       = (const float*)d_in[0];
  const float* ela       = (const float*)d_in[1];
  const float* cur_dist  = (const float*)d_in[2];
  const float* ninf      = (const float*)d_in[3];
  const float* lengths   = (const float*)d_in[4];
  const float* max_dis   = (const float*)d_in[5];
  const float* remain    = (const float*)d_in[6];
  const float* q_first   = (const float*)d_in[7];
  const float* kten      = (const float*)d_in[8];
  const float* vten      = (const float*)d_in[9];
  const float* shk       = (const float*)d_in[10];
  const float* Wq        = (const float*)d_in[11];
  const float* dis_emb   = (const float*)d_in[12];
  const float* mh_w      = (const float*)d_in[13];
  const float* mh_b      = (const float*)d_in[14];
  const float* dalpha    = (const float*)d_in[15];
  const int*   depot     = (const int*)d_in[16];
  const int*   route_cnt = (const int*)d_in[17];
  const int*   left_city = (const int*)d_in[18];
  const int*   city_num  = (const int*)d_in[19];
  float* out = (float*)d_out;

  float* ws      = (float*)d_ws;
  float* q_ws    = ws;                                   // 6400*512
  float* attn_ws = q_ws + (size_t)ROWS * 512;            // 6400*512
  float* mh_ws   = attn_ws + (size_t)ROWS * 512;         // 6400*512
  float* sc_ws   = mh_ws + (size_t)ROWS * 512;           // 6400*1000
  float* rmax_ws = sc_ws + (size_t)ROWS * NN;            // 6400

  k_rowmax<<<ROWS / 4, 256, 0, stream>>>(cur_dist, rmax_ws);
  k_qgemm<<<dim3(8, 100), 256, 0, stream>>>(eln, ela, lengths, max_dis, remain,
                                            q_first, Wq, dis_emb, depot, route_cnt,
                                            left_city, city_num, q_ws);
  k_attn<<<BB * HH * 2, 256, 0, stream>>>(q_ws, kten, vten, ninf, attn_ws);
  k_mhgemm<<<dim3(8, 100), 256, 0, stream>>>(attn_ws, mh_w, mh_b, mh_ws);
  k_final_score<<<dim3(4, 7, 64), 256, 0, stream>>>(mh_ws, shk, cur_dist, rmax_ws,
                                                    ninf, dalpha, sc_ws);
  k_softmax<<<ROWS, 256, 0, stream>>>(sc_ws, out);
}

// Round 6
// 833.055 us; speedup vs baseline: 4.6901x; 1.2428x over previous
//
#include <hip/hip_runtime.h>
#include <hip/hip_bf16.h>

#define BB 64
#define PP 100
#define NN 1000
#define EE 512
#define HH 8
#define KDD 64
#define MM 10
#define ROWS (BB*PP)          // 6400
#define K1K 1026              // 2E+2
#define INVSQE 0.044194173824159216f  // 1/sqrt(512)
#define CLIPV 10.0f

union F4 { float4 v; float f[4]; };

using bf16x8 = __attribute__((ext_vector_type(8))) short;
using f32x4  = __attribute__((ext_vector_type(4))) float;

__device__ inline unsigned short f2bf(float x) {
  unsigned u = __float_as_uint(x);
  u += 0x7FFFu + ((u >> 16) & 1u);
  return (unsigned short)(u >> 16);
}

// ---------------------------------------------------------------- K0: row max of cur_dist
__global__ __launch_bounds__(256) void k_rowmax(const float* __restrict__ cd,
                                                float* __restrict__ rmax) {
  int row = blockIdx.x * 4 + (threadIdx.x >> 6);
  int lane = threadIdx.x & 63;
  const float* src = cd + (size_t)row * NN;
  float m = -1e30f;
  for (int i = lane; i < NN; i += 64) m = fmaxf(m, src[i]);
  #pragma unroll
  for (int off = 32; off; off >>= 1) m = fmaxf(m, __shfl_xor(m, off));
  if (lane == 0) rmax[row] = m;
}

// ---------------------------------------------------------------- K1: q = q_first + heads(X @ Wq^T) + heads(info @ dis_emb^T)
__global__ __launch_bounds__(256) void k_qgemm(
    const float* __restrict__ eln, const float* __restrict__ ela,
    const float* __restrict__ lengths, const float* __restrict__ max_dis,
    const float* __restrict__ remain, const float* __restrict__ q_first,
    const float* __restrict__ Wq, const float* __restrict__ dis_emb,
    const int* __restrict__ depot, const int* __restrict__ route_cnt,
    const int* __restrict__ left_city, const int* __restrict__ city_num,
    float* __restrict__ qout) {
  __shared__ float Xs[64][36];
  __shared__ float Ws[64][36];
  __shared__ float info_s[64][4];
  __shared__ float fl_s[64][2];
  const int t = threadIdx.x;
  const int rowBase = blockIdx.y * 64, colBase = blockIdx.x * 64;
  if (t < 64) {
    int row = rowBase + t;
    int b = row / PP;
    int rc = route_cnt[row];
    int rn = depot[b] - 1;
    info_s[t][0] = lengths[row * MM + rc];
    info_s[t][1] = lengths[row * MM + rn];
    info_s[t][2] = max_dis[row];
    info_s[t][3] = remain[row];
    fl_s[t][0] = 1.0f - (float)(rc + 1) / (float)(rn + 1);
    fl_s[t][1] = (float)left_city[row] / (float)city_num[0];
  }
  __syncthreads();
  float acc[4][4];
  #pragma unroll
  for (int i = 0; i < 4; ++i)
    #pragma unroll
    for (int j = 0; j < 4; ++j) acc[i][j] = 0.f;
  const int tx = t & 15, ty = t >> 4;
  for (int kt = 0; kt < 33; ++kt) {
    const int k0 = kt * 32;
    #pragma unroll
    for (int i = 0; i < 8; ++i) {
      int e = i * 256 + t;
      int r = e >> 5, c = e & 31;
      int j = k0 + c;
      int row = rowBase + r;
      float xv;
      if (j < 512)       xv = eln[(size_t)row * 512 + j];
      else if (j < 1024) xv = ela[(size_t)row * 512 + j - 512];
      else if (j == 1024) xv = fl_s[r][0];
      else if (j == 1025) xv = fl_s[r][1];
      else xv = 0.f;
      Xs[r][c] = xv;
      Ws[r][c] = (j < K1K) ? Wq[(size_t)(colBase + r) * K1K + j] : 0.f;
    }
    __syncthreads();
    #pragma unroll
    for (int kc = 0; kc < 32; kc += 4) {
      F4 xv[4], wv[4];
      #pragma unroll
      for (int i = 0; i < 4; ++i) xv[i].v = *(const float4*)&Xs[ty + 16 * i][kc];
      #pragma unroll
      for (int j = 0; j < 4; ++j) wv[j].v = *(const float4*)&Ws[tx + 16 * j][kc];
      #pragma unroll
      for (int c = 0; c < 4; ++c)
        #pragma unroll
        for (int i = 0; i < 4; ++i)
          #pragma unroll
          for (int j = 0; j < 4; ++j)
            acc[i][j] += xv[i].f[c] * wv[j].f[c];
    }
    __syncthreads();
  }
  #pragma unroll
  for (int i = 0; i < 4; ++i) {
    int r = ty + 16 * i;
    int row = rowBase + r;
    int b = row / PP, p = row % PP;
    F4 inf; inf.v = *(const float4*)&info_s[r][0];
    #pragma unroll
    for (int j = 0; j < 4; ++j) {
      int o = colBase + tx + 16 * j;
      F4 de; de.v = *(const float4*)&dis_emb[(size_t)o * 4];
      float v = acc[i][j]
              + inf.f[0] * de.f[0] + inf.f[1] * de.f[1]
              + inf.f[2] * de.f[2] + inf.f[3] * de.f[3]
              + q_first[(((size_t)b * HH + (o >> 6)) * PP + p) * KDD + (o & 63)];
      qout[(size_t)row * 512 + o] = v;
    }
  }
}

// ---------------------------------------------------------------- K2: masked MHA via MFMA bf16 (16x16x32)
// One block per (b,h), 4 waves. P padded to 112 = 7 m-tiles of 16; wave w owns
// tiles {w, w+4}. N chunks of 64 (2 k-slices of 32, 4 n-tiles of 16).
// Fragment layouts (gfx950 mfma_f32_16x16x32_bf16):
//   A: row = lane&15, k = (lane>>4)*8 + i
//   B: col = lane&15, k = (lane>>4)*8 + i
//   C/D: col = lane&15, row = (lane>>4)*4 + j    [learn_hip m89 verified]
// LESSONS: no min-waves launch_bounds (round 2); mask staged in LDS, never
// per-thread global loads in-loop (round 3). PM buffer serves Q staging ->
// per-chunk mask -> overwritten in place by exp weights (lane-exclusive cells).
__global__ __launch_bounds__(256) void k_attn(
    const float* __restrict__ qin, const float* __restrict__ kk,
    const float* __restrict__ vv, const float* __restrict__ mask,
    float* __restrict__ attn_out) {
  __shared__ unsigned short Kl[64][72];   // bf16 K chunk [n][d], 16B-aligned rows
  __shared__ unsigned short Vt[64][72];   // bf16 V^T chunk [d][n]
  __shared__ float PM[112][68];           // Q stage -> mask -> P (fp32)

  const int t = threadIdx.x;
  const int lane = t & 63;
  const int w = t >> 6;            // wave 0..3
  const int lr = lane & 15;
  const int lg = lane >> 4;
  const int bh = blockIdx.x, b = bh >> 3, h = bh & 7;

  // ---- stage Q (fp32, scaled 1/8) into PM rows 0..111
  #pragma unroll
  for (int i = 0; i < 7; ++i) {
    int idx = i * 256 + t;              // 112*16 = 1792
    int r = idx >> 4, c4 = (idx & 15) * 4;
    float4 qv = make_float4(0.f, 0.f, 0.f, 0.f);
    if (r < PP)
      qv = *(const float4*)&qin[((size_t)(b * PP + r)) * 512 + h * 64 + c4];
    qv.x *= 0.125f; qv.y *= 0.125f; qv.z *= 0.125f; qv.w *= 0.125f;
    *(float4*)&PM[r][c4] = qv;
  }
  __syncthreads();

  // ---- per-wave Q A-frags: qf[u][kb], tile tt = w + 4u
  bf16x8 qf[2][2];
  #pragma unroll
  for (int u = 0; u < 2; ++u) {
    int tt = w + 4 * u;
    if (tt < 7) {
      #pragma unroll
      for (int kb = 0; kb < 2; ++kb) {
        F4 p0, p1;
        p0.v = *(const float4*)&PM[tt * 16 + lr][kb * 32 + lg * 8];
        p1.v = *(const float4*)&PM[tt * 16 + lr][kb * 32 + lg * 8 + 4];
        bf16x8 f;
        #pragma unroll
        for (int i = 0; i < 4; ++i) { f[i] = (short)f2bf(p0.f[i]); f[i + 4] = (short)f2bf(p1.f[i]); }
        qf[u][kb] = f;
      }
    }
  }
  __syncthreads();   // Q reads done before PM becomes mask buffer

  float Mx[2][4], Lx[2][4];
  f32x4 Oa[2][4];
  #pragma unroll
  for (int u = 0; u < 2; ++u)
    #pragma unroll
    for (int j = 0; j < 4; ++j) {
      Mx[u][j] = -1e30f; Lx[u][j] = 0.f;
      Oa[u][j][0] = 0.f; Oa[u][j][1] = 0.f; Oa[u][j][2] = 0.f; Oa[u][j][3] = 0.f;
    }

  for (int ch = 0; ch < 16; ++ch) {
    const int n0 = ch * 64;

    // ---- stage K row-major bf16 (coalesced)
    #pragma unroll
    for (int i = 0; i < 4; ++i) {
      int idx = i * 256 + t;
      int r = idx >> 4, c4 = (idx & 15) * 4;
      int n = n0 + r;
      F4 kv; kv.v = make_float4(0.f, 0.f, 0.f, 0.f);
      if (n < NN) kv.v = *(const float4*)&kk[(((size_t)bh * NN) + n) * 64 + c4];
      Kl[r][c4 + 0] = f2bf(kv.f[0]); Kl[r][c4 + 1] = f2bf(kv.f[1]);
      Kl[r][c4 + 2] = f2bf(kv.f[2]); Kl[r][c4 + 3] = f2bf(kv.f[3]);
    }
    // ---- stage V transposed bf16: thread (a = t>>4 n-block, b2 = t&15 d-block)
    {
      int a = t >> 4, b2 = t & 15;
      F4 rowv[4];
      #pragma unroll
      for (int r = 0; r < 4; ++r) {
        int n = n0 + 4 * a + r;
        rowv[r].v = (n < NN) ? *(const float4*)&vv[(((size_t)bh * NN) + n) * 64 + 4 * b2]
                             : make_float4(0.f, 0.f, 0.f, 0.f);
      }
      #pragma unroll
      for (int c = 0; c < 4; ++c) {
        unsigned short* dst = &Vt[4 * b2 + c][4 * a];
        dst[0] = f2bf(rowv[0].f[c]); dst[1] = f2bf(rowv[1].f[c]);
        dst[2] = f2bf(rowv[2].f[c]); dst[3] = f2bf(rowv[3].f[c]);
      }
    }
    // ---- stage mask chunk fp32 into PM (rows >= PP -> 0; cols >= NN -> -1e30)
    #pragma unroll
    for (int i = 0; i < 7; ++i) {
      int idx = i * 256 + t;
      int r = idx >> 4, c4 = (idx & 15) * 4;
      int n = n0 + c4;
      F4 mv; mv.v = make_float4(0.f, 0.f, 0.f, 0.f);
      if (r < PP) {
        if (n + 3 < NN) {
          mv.v = *(const float4*)&mask[((size_t)(b * PP + r)) * NN + n];
        } else {
          #pragma unroll
          for (int j = 0; j < 4; ++j)
            mv.f[j] = (n + j < NN) ? mask[((size_t)(b * PP + r)) * NN + n + j] : -1e30f;
        }
      }
      *(float4*)&PM[r][c4] = mv.v;
    }
    __syncthreads();

    // ---- QK^T mfma + online softmax (P written back into PM in place)
    float rsv[2][4];
    #pragma unroll
    for (int u = 0; u < 2; ++u) {
      int tt = w + 4 * u;
      if (tt >= 7) continue;
      f32x4 sa[4];
      #pragma unroll
      for (int nb = 0; nb < 4; ++nb) { sa[nb][0] = 0.f; sa[nb][1] = 0.f; sa[nb][2] = 0.f; sa[nb][3] = 0.f; }
      #pragma unroll
      for (int kb = 0; kb < 2; ++kb)
        #pragma unroll
        for (int nb = 0; nb < 4; ++nb) {
          bf16x8 kf = *(bf16x8*)&Kl[nb * 16 + lr][kb * 32 + lg * 8];
          sa[nb] = __builtin_amdgcn_mfma_f32_16x16x32_bf16(qf[u][kb], kf, sa[nb], 0, 0, 0);
        }
      #pragma unroll
      for (int j = 0; j < 4; ++j) {
        int pl = tt * 16 + lg * 4 + j;
        float s0 = sa[0][j] + PM[pl][lr];
        float s1 = sa[1][j] + PM[pl][16 + lr];
        float s2 = sa[2][j] + PM[pl][32 + lr];
        float s3 = sa[3][j] + PM[pl][48 + lr];
        float cm = fmaxf(fmaxf(s0, s1), fmaxf(s2, s3));
        #pragma unroll
        for (int off = 1; off < 16; off <<= 1) cm = fmaxf(cm, __shfl_xor(cm, off));
        float Mn = fmaxf(Mx[u][j], cm);
        float r = __expf(Mx[u][j] - Mn);
        float e0 = __expf(s0 - Mn), e1 = __expf(s1 - Mn);
        float e2 = __expf(s2 - Mn), e3 = __expf(s3 - Mn);
        float sum = (e0 + e1) + (e2 + e3);
        #pragma unroll
        for (int off = 1; off < 16; off <<= 1) sum += __shfl_xor(sum, off);
        Lx[u][j] = Lx[u][j] * r + sum;
        Mx[u][j] = Mn;
        rsv[u][j] = r;
        PM[pl][lr] = e0; PM[pl][16 + lr] = e1; PM[pl][32 + lr] = e2; PM[pl][48 + lr] = e3;
      }
    }
    __syncthreads();   // P visible (same-wave cells only, but keep waves in step)

    // ---- PV mfma: O += P @ V
    #pragma unroll
    for (int u = 0; u < 2; ++u) {
      int tt = w + 4 * u;
      if (tt >= 7) continue;
      #pragma unroll
      for (int dt = 0; dt < 4; ++dt) {
        f32x4 o = Oa[u][dt];
        o[0] *= rsv[u][0]; o[1] *= rsv[u][1]; o[2] *= rsv[u][2]; o[3] *= rsv[u][3];
        Oa[u][dt] = o;
      }
      #pragma unroll
      for (int kb = 0; kb < 2; ++kb) {
        F4 p0, p1;
        p0.v = *(const float4*)&PM[tt * 16 + lr][kb * 32 + lg * 8];
        p1.v = *(const float4*)&PM[tt * 16 + lr][kb * 32 + lg * 8 + 4];
        bf16x8 pf;
        #pragma unroll
        for (int i = 0; i < 4; ++i) { pf[i] = (short)f2bf(p0.f[i]); pf[i + 4] = (short)f2bf(p1.f[i]); }
        #pragma unroll
        for (int dt = 0; dt < 4; ++dt) {
          bf16x8 vf = *(bf16x8*)&Vt[dt * 16 + lr][kb * 32 + lg * 8];
          Oa[u][dt] = __builtin_amdgcn_mfma_f32_16x16x32_bf16(pf, vf, Oa[u][dt], 0, 0, 0);
        }
      }
    }
    __syncthreads();   // protect Kl/Vt/PM before next chunk staging
  }

  // ---- epilogue: O / L
  #pragma unroll
  for (int u = 0; u < 2; ++u) {
    int tt = w + 4 * u;
    if (tt >= 7) continue;
    #pragma unroll
    for (int j = 0; j < 4; ++j) {
      int p = tt * 16 + lg * 4 + j;
      if (p >= PP) continue;
      float L = Lx[u][j];
      float inv = (L > 0.f) ? 1.0f / L : 0.f;
      #pragma unroll
      for (int dt = 0; dt < 4; ++dt)
        attn_out[((size_t)(b * PP + p)) * 512 + h * 64 + dt * 16 + lr] = Oa[u][dt][j] * inv;
    }
  }
}

// ---------------------------------------------------------------- K3: mh = attn_out @ mh_w^T + mh_b
__global__ __launch_bounds__(256) void k_mhgemm(
    const float* __restrict__ A, const float* __restrict__ W,
    const float* __restrict__ bias, float* __restrict__ out) {
  __shared__ float Xs[64][36];
  __shared__ float Ws[64][36];
  const int t = threadIdx.x;
  const int rowBase = blockIdx.y * 64, colBase = blockIdx.x * 64;
  const int tx = t & 15, ty = t >> 4;
  float acc[4][4];
  #pragma unroll
  for (int i = 0; i < 4; ++i)
    #pragma unroll
    for (int j = 0; j < 4; ++j) acc[i][j] = 0.f;
  for (int kt = 0; kt < 16; ++kt) {
    const int k0 = kt * 32;
    #pragma unroll
    for (int i = 0; i < 8; ++i) {
      int e = i * 256 + t;
      int r = e >> 5, c = e & 31;
      Xs[r][c] = A[(size_t)(rowBase + r) * 512 + k0 + c];
      Ws[r][c] = W[(size_t)(colBase + r) * 512 + k0 + c];
    }
    __syncthreads();
    #pragma unroll
    for (int kc = 0; kc < 32; kc += 4) {
      F4 xv[4], wv[4];
      #pragma unroll
      for (int i = 0; i < 4; ++i) xv[i].v = *(const float4*)&Xs[ty + 16 * i][kc];
      #pragma unroll
      for (int j = 0; j < 4; ++j) wv[j].v = *(const float4*)&Ws[tx + 16 * j][kc];
      #pragma unroll
      for (int c = 0; c < 4; ++c)
        #pragma unroll
        for (int i = 0; i < 4; ++i)
          #pragma unroll
          for (int j = 0; j < 4; ++j)
            acc[i][j] += xv[i].f[c] * wv[j].f[c];
    }
    __syncthreads();
  }
  #pragma unroll
  for (int i = 0; i < 4; ++i) {
    int row = rowBase + ty + 16 * i;
    #pragma unroll
    for (int j = 0; j < 4; ++j) {
      int o = colBase + tx + 16 * j;
      out[(size_t)row * 512 + o] = acc[i][j] + bias[o];
    }
  }
}

// ---------------------------------------------------------------- K4a: score2 = mh @ shk, then 10*tanh(s/sqrtE - a*cd/cdmax) + mask
__global__ __launch_bounds__(256) void k_final_score(
    const float* __restrict__ mh, const float* __restrict__ shk,
    const float* __restrict__ cur_dist, const float* __restrict__ rmax,
    const float* __restrict__ mask, const float* __restrict__ dist_alpha,
    float* __restrict__ sc_out) {
  __shared__ float mh_s[16][36];
  __shared__ float shk_s[32][260];
  const int t = threadIdx.x;
  const int b = blockIdx.z, p0 = blockIdx.y * 16, n0 = blockIdx.x * 256;
  const int pg = t >> 6, ng = t & 63;
  float acc[4][4];
  #pragma unroll
  for (int i = 0; i < 4; ++i)
    #pragma unroll
    for (int j = 0; j < 4; ++j) acc[i][j] = 0.f;
  for (int kt = 0; kt < 16; ++kt) {
    const int k0 = kt * 32;
    if (t < 128) {
      int r = t >> 3, c4 = (t & 7) * 4;
      float4 mv = make_float4(0.f, 0.f, 0.f, 0.f);
      if (p0 + r < PP) mv = *(const float4*)&mh[((size_t)(b * PP + p0 + r)) * 512 + k0 + c4];
      *(float4*)&mh_s[r][c4] = mv;
    }
    #pragma unroll
    for (int i = 0; i < 8; ++i) {
      int idx = i * 256 + t;
      int e = idx >> 6, n4 = (idx & 63) * 4;
      int n = n0 + n4;
      const float* src = &shk[((size_t)(b * 512 + k0 + e)) * NN + n];
      float4 sv = make_float4(0.f, 0.f, 0.f, 0.f);
      if (n + 3 < NN) sv = *(const float4*)src;
      else if (n < NN) {
        sv.x = src[0];
        if (n + 1 < NN) sv.y = src[1];
        if (n + 2 < NN) sv.z = src[2];
      }
      *(float4*)&shk_s[e][n4] = sv;
    }
    __syncthreads();
    #pragma unroll
    for (int k = 0; k < 32; k += 4) {
      F4 a0, a1, a2, a3;
      a0.v = *(const float4*)&mh_s[pg * 4 + 0][k];
      a1.v = *(const float4*)&mh_s[pg * 4 + 1][k];
      a2.v = *(const float4*)&mh_s[pg * 4 + 2][k];
      a3.v = *(const float4*)&mh_s[pg * 4 + 3][k];
      #pragma unroll
      for (int kk = 0; kk < 4; ++kk) {
        F4 bv; bv.v = *(const float4*)&shk_s[k + kk][ng * 4];
        #pragma unroll
        for (int c = 0; c < 4; ++c) {
          acc[0][c] += a0.f[kk] * bv.f[c];
          acc[1][c] += a1.f[kk] * bv.f[c];
          acc[2][c] += a2.f[kk] * bv.f[c];
          acc[3][c] += a3.f[kk] * bv.f[c];
        }
      }
    }
    __syncthreads();
  }
  const float alpha = dist_alpha[0];
  #pragma unroll
  for (int i = 0; i < 4; ++i) {
    int p = p0 + pg * 4 + i;
    if (p >= PP) continue;
    size_t rb = (size_t)(b * PP + p) * NN;
    float rmx = rmax[b * PP + p];
    int n = n0 + ng * 4;
    if (n >= NN) continue;
    if (n + 3 < NN) {
      F4 cd, mk, o;
      cd.v = *(const float4*)&cur_dist[rb + n];
      mk.v = *(const float4*)&mask[rb + n];
      #pragma unroll
      for (int j = 0; j < 4; ++j)
        o.f[j] = CLIPV * tanhf(acc[i][j] * INVSQE - alpha * cd.f[j] / rmx) + mk.f[j];
      *(float4*)&sc_out[rb + n] = o.v;
    } else {
      #pragma unroll
      for (int j = 0; j < 4; ++j) {
        if (n + j < NN) {
          float cd = cur_dist[rb + n + j];
          float mk = mask[rb + n + j];
          sc_out[rb + n + j] = CLIPV * tanhf(acc[i][j] * INVSQE - alpha * cd / rmx) + mk;
        }
      }
    }
  }
}

// ---------------------------------------------------------------- K4b: row softmax over N
__global__ __launch_bounds__(256) void k_softmax(const float* __restrict__ sc,
                                                 float* __restrict__ out) {
  __shared__ float redm[4];
  __shared__ float redsum[4];
  const int row = blockIdx.x;
  const int t = threadIdx.x;
  const float* src = sc + (size_t)row * NN;
  float v0[4];
  float m = -1e30f;
  #pragma unroll
  for (int i = 0; i < 4; ++i) {
    int n = i * 256 + t;
    v0[i] = (n < NN) ? src[n] : -1e30f;
    m = fmaxf(m, v0[i]);
  }
  #pragma unroll
  for (int off = 32; off; off >>= 1) m = fmaxf(m, __shfl_xor(m, off));
  int wid = t >> 6, lane = t & 63;
  if (lane == 0) redm[wid] = m;
  __syncthreads();
  m = fmaxf(fmaxf(redm[0], redm[1]), fmaxf(redm[2], redm[3]));
  float e[4];
  float s = 0.f;
  #pragma unroll
  for (int i = 0; i < 4; ++i) {
    int n = i * 256 + t;
    e[i] = (n < NN) ? __expf(v0[i] - m) : 0.f;
    s += e[i];
  }
  #pragma unroll
  for (int off = 32; off; off >>= 1) s += __shfl_xor(s, off);
  if (lane == 0) redsum[wid] = s;
  __syncthreads();
  s = redsum[0] + redsum[1] + redsum[2] + redsum[3];
  float inv = 1.0f / s;
  #pragma unroll
  for (int i = 0; i < 4; ++i) {
    int n = i * 256 + t;
    if (n < NN) out[(size_t)row * NN + n] = e[i] * inv;
  }
}

// ----------------------------------------------------------------
extern "C" void kernel_launch(void* const* d_in, const int* in_sizes, int n_in,
                              void* d_out, int out_size, void* d_ws, size_t ws_size,
                              hipStream_t stream) {
  const float* eln       = (const float*)d_in[0];
  const float* ela       = (const float*)d_in[1];
  const float* cur_dist  = (const float*)d_in[2];
  const float* ninf      = (const float*)d_in[3];
  const float* lengths   = (const float*)d_in[4];
  const float* max_dis   = (const float*)d_in[5];
  const float* remain    = (const float*)d_in[6];
  const float* q_first   = (const float*)d_in[7];
  const float* kten      = (const float*)d_in[8];
  const float* vten      = (const float*)d_in[9];
  const float* shk       = (const float*)d_in[10];
  const float* Wq        = (const float*)d_in[11];
  const float* dis_emb   = (const float*)d_in[12];
  const float* mh_w      = (const float*)d_in[13];
  const float* mh_b      = (const float*)d_in[14];
  const float* dalpha    = (const float*)d_in[15];
  const int*   depot     = (const int*)d_in[16];
  const int*   route_cnt = (const int*)d_in[17];
  const int*   left_city = (const int*)d_in[18];
  const int*   city_num  = (const int*)d_in[19];
  float* out = (float*)d_out;

  float* ws      = (float*)d_ws;
  float* q_ws    = ws;                                   // 6400*512
  float* attn_ws = q_ws + (size_t)ROWS * 512;            // 6400*512
  float* mh_ws   = attn_ws + (size_t)ROWS * 512;         // 6400*512
  float* sc_ws   = mh_ws + (size_t)ROWS * 512;           // 6400*1000
  float* rmax_ws = sc_ws + (size_t)ROWS * NN;            // 6400

  k_rowmax<<<ROWS / 4, 256, 0, stream>>>(cur_dist, rmax_ws);
  k_qgemm<<<dim3(8, 100), 256, 0, stream>>>(eln, ela, lengths, max_dis, remain,
                                            q_first, Wq, dis_emb, depot, route_cnt,
                                            left_city, city_num, q_ws);
  k_attn<<<BB * HH, 256, 0, stream>>>(q_ws, kten, vten, ninf, attn_ws);
  k_mhgemm<<<dim3(8, 100), 256, 0, stream>>>(attn_ws, mh_w, mh_b, mh_ws);
  k_final_score<<<dim3(4, 7, 64), 256, 0, stream>>>(mh_ws, shk, cur_dist, rmax_ws,
                                                    ninf, dalpha, sc_ws);
  k_softmax<<<ROWS, 256, 0, stream>>>(sc_ws, out);
}

// Round 7
// 320.202 us; speedup vs baseline: 12.2021x; 2.6017x over previous
//
#include <hip/hip_runtime.h>
#include <hip/hip_bf16.h>

#define BB 64
#define PP 100
#define NN 1000
#define EE 512
#define HH 8
#define KDD 64
#define MM 10
#define ROWS (BB*PP)          // 6400
#define K1K 1026              // 2E+2
#define INVSQE 0.044194173824159216f  // 1/sqrt(512)
#define CLIPV 10.0f

union F4 { float4 v; float f[4]; };

using bf16x8 = __attribute__((ext_vector_type(8))) short;
using f32x4  = __attribute__((ext_vector_type(4))) float;

__device__ inline unsigned short f2bf(float x) {
  unsigned u = __float_as_uint(x);
  u += 0x7FFFu + ((u >> 16) & 1u);
  return (unsigned short)(u >> 16);
}

__device__ inline float fast_tanh(float x) {
  // tanh(x) = 1 - 2/(e^{2x}+1); saturates correctly for |x| large (inf -> 1)
  float e = __expf(2.0f * x);
  return 1.0f - 2.0f / (e + 1.0f);
}

// ---------------------------------------------------------------- K0: row max of cur_dist
__global__ __launch_bounds__(256) void k_rowmax(const float* __restrict__ cd,
                                                float* __restrict__ rmax) {
  int row = blockIdx.x * 4 + (threadIdx.x >> 6);
  int lane = threadIdx.x & 63;
  const float* src = cd + (size_t)row * NN;
  float m = -1e30f;
  for (int i = lane; i < NN; i += 64) m = fmaxf(m, src[i]);
  #pragma unroll
  for (int off = 32; off; off >>= 1) m = fmaxf(m, __shfl_xor(m, off));
  if (lane == 0) rmax[row] = m;
}

// ---------------------------------------------------------------- K1: q = q_first + heads(X @ Wq^T) + heads(info @ dis_emb^T)
// MFMA bf16. Block 64x64 tile, 4 waves; wave w owns n-tile w (16 cols),
// computes 4 m-tiles. K main loop = 1024 (eln cols 0-511, ela 512-1023);
// cols 1024 (frac) / 1025 (lc) are a rank-2 update in the epilogue.
// Fragment convention (verified by k_attn r6): mfma(A,B,C): A lane lr = m-row,
// B lane lr = n-col, k = lg*8+i; D: col=lr, row=lg*4+j.
__global__ __launch_bounds__(256) void k_qgemm(
    const float* __restrict__ eln, const float* __restrict__ ela,
    const float* __restrict__ lengths, const float* __restrict__ max_dis,
    const float* __restrict__ remain, const float* __restrict__ q_first,
    const float* __restrict__ Wq, const float* __restrict__ dis_emb,
    const int* __restrict__ depot, const int* __restrict__ route_cnt,
    const int* __restrict__ left_city, const int* __restrict__ city_num,
    float* __restrict__ qout) {
  __shared__ unsigned short Xs[64][40];
  __shared__ unsigned short Ws[64][40];
  __shared__ float info_s[64][4];
  __shared__ float fl_s[64][2];
  const int t = threadIdx.x;
  const int lane = t & 63;
  const int w = t >> 6;
  const int lr = lane & 15, lg = lane >> 4;
  const int rowBase = blockIdx.y * 64, colBase = blockIdx.x * 64;

  if (t < 64) {
    int row = rowBase + t;
    int b = row / PP;
    int rc = route_cnt[row];
    int rn = depot[b] - 1;
    info_s[t][0] = lengths[row * MM + rc];
    info_s[t][1] = lengths[row * MM + rn];
    info_s[t][2] = max_dis[row];
    info_s[t][3] = remain[row];
    fl_s[t][0] = 1.0f - (float)(rc + 1) / (float)(rn + 1);
    fl_s[t][1] = (float)left_city[row] / (float)city_num[0];
  }

  f32x4 acc[4];
  #pragma unroll
  for (int m = 0; m < 4; ++m) { acc[m][0] = 0.f; acc[m][1] = 0.f; acc[m][2] = 0.f; acc[m][3] = 0.f; }

  for (int kt = 0; kt < 32; ++kt) {
    const float* xsrc = (kt < 16) ? eln : ela;
    const int koff = (kt & 15) * 32;
    __syncthreads();   // protect LDS from previous iteration's readers
    #pragma unroll
    for (int i = 0; i < 2; ++i) {
      int s = i * 256 + t;              // 512 float4 slots
      int r = s >> 3, c4 = (s & 7) * 4;
      F4 xv, wv;
      xv.v = *(const float4*)&xsrc[(size_t)(rowBase + r) * 512 + koff + c4];
      wv.v = *(const float4*)&Wq[(size_t)(colBase + r) * K1K + kt * 32 + c4];
      unsigned short* xd = &Xs[r][c4];
      unsigned short* wd = &Ws[r][c4];
      xd[0] = f2bf(xv.f[0]); xd[1] = f2bf(xv.f[1]); xd[2] = f2bf(xv.f[2]); xd[3] = f2bf(xv.f[3]);
      wd[0] = f2bf(wv.f[0]); wd[1] = f2bf(wv.f[1]); wd[2] = f2bf(wv.f[2]); wd[3] = f2bf(wv.f[3]);
    }
    __syncthreads();
    bf16x8 bfr = *(bf16x8*)&Ws[w * 16 + lr][lg * 8];
    #pragma unroll
    for (int m = 0; m < 4; ++m) {
      bf16x8 af = *(bf16x8*)&Xs[m * 16 + lr][lg * 8];
      acc[m] = __builtin_amdgcn_mfma_f32_16x16x32_bf16(af, bfr, acc[m], 0, 0, 0);
    }
  }

  // epilogue
  const int o = colBase + w * 16 + lr;          // output col; h = o>>6 = blockIdx.x when 8 n-blocks
  F4 de; de.v = *(const float4*)&dis_emb[(size_t)o * 4];
  const float wq1024 = Wq[(size_t)o * K1K + 1024];
  const float wq1025 = Wq[(size_t)o * K1K + 1025];
  const int h = o >> 6, kd = o & 63;
  #pragma unroll
  for (int m = 0; m < 4; ++m) {
    #pragma unroll
    for (int j = 0; j < 4; ++j) {
      int r = m * 16 + lg * 4 + j;
      int row = rowBase + r;
      int b = row / PP, p = row % PP;
      F4 inf; inf.v = *(const float4*)&info_s[r][0];
      float v = acc[m][j]
              + inf.f[0] * de.f[0] + inf.f[1] * de.f[1]
              + inf.f[2] * de.f[2] + inf.f[3] * de.f[3]
              + fl_s[r][0] * wq1024 + fl_s[r][1] * wq1025
              + q_first[(((size_t)b * HH + h) * PP + p) * KDD + kd];
      qout[(size_t)row * 512 + o] = v;
    }
  }
}

// ---------------------------------------------------------------- K2: masked MHA via MFMA bf16 (16x16x32)  [round-6, working]
__global__ __launch_bounds__(256) void k_attn(
    const float* __restrict__ qin, const float* __restrict__ kk,
    const float* __restrict__ vv, const float* __restrict__ mask,
    float* __restrict__ attn_out) {
  __shared__ unsigned short Kl[64][72];
  __shared__ unsigned short Vt[64][72];
  __shared__ float PM[112][68];

  const int t = threadIdx.x;
  const int lane = t & 63;
  const int w = t >> 6;
  const int lr = lane & 15;
  const int lg = lane >> 4;
  const int bh = blockIdx.x, b = bh >> 3, h = bh & 7;

  #pragma unroll
  for (int i = 0; i < 7; ++i) {
    int idx = i * 256 + t;
    int r = idx >> 4, c4 = (idx & 15) * 4;
    float4 qv = make_float4(0.f, 0.f, 0.f, 0.f);
    if (r < PP)
      qv = *(const float4*)&qin[((size_t)(b * PP + r)) * 512 + h * 64 + c4];
    qv.x *= 0.125f; qv.y *= 0.125f; qv.z *= 0.125f; qv.w *= 0.125f;
    *(float4*)&PM[r][c4] = qv;
  }
  __syncthreads();

  bf16x8 qf[2][2];
  #pragma unroll
  for (int u = 0; u < 2; ++u) {
    int tt = w + 4 * u;
    if (tt < 7) {
      #pragma unroll
      for (int kb = 0; kb < 2; ++kb) {
        F4 p0, p1;
        p0.v = *(const float4*)&PM[tt * 16 + lr][kb * 32 + lg * 8];
        p1.v = *(const float4*)&PM[tt * 16 + lr][kb * 32 + lg * 8 + 4];
        bf16x8 f;
        #pragma unroll
        for (int i = 0; i < 4; ++i) { f[i] = (short)f2bf(p0.f[i]); f[i + 4] = (short)f2bf(p1.f[i]); }
        qf[u][kb] = f;
      }
    }
  }
  __syncthreads();

  float Mx[2][4], Lx[2][4];
  f32x4 Oa[2][4];
  #pragma unroll
  for (int u = 0; u < 2; ++u)
    #pragma unroll
    for (int j = 0; j < 4; ++j) {
      Mx[u][j] = -1e30f; Lx[u][j] = 0.f;
      Oa[u][j][0] = 0.f; Oa[u][j][1] = 0.f; Oa[u][j][2] = 0.f; Oa[u][j][3] = 0.f;
    }

  for (int ch = 0; ch < 16; ++ch) {
    const int n0 = ch * 64;
    #pragma unroll
    for (int i = 0; i < 4; ++i) {
      int idx = i * 256 + t;
      int r = idx >> 4, c4 = (idx & 15) * 4;
      int n = n0 + r;
      F4 kv; kv.v = make_float4(0.f, 0.f, 0.f, 0.f);
      if (n < NN) kv.v = *(const float4*)&kk[(((size_t)bh * NN) + n) * 64 + c4];
      Kl[r][c4 + 0] = f2bf(kv.f[0]); Kl[r][c4 + 1] = f2bf(kv.f[1]);
      Kl[r][c4 + 2] = f2bf(kv.f[2]); Kl[r][c4 + 3] = f2bf(kv.f[3]);
    }
    {
      int a = t >> 4, b2 = t & 15;
      F4 rowv[4];
      #pragma unroll
      for (int r = 0; r < 4; ++r) {
        int n = n0 + 4 * a + r;
        rowv[r].v = (n < NN) ? *(const float4*)&vv[(((size_t)bh * NN) + n) * 64 + 4 * b2]
                             : make_float4(0.f, 0.f, 0.f, 0.f);
      }
      #pragma unroll
      for (int c = 0; c < 4; ++c) {
        unsigned short* dst = &Vt[4 * b2 + c][4 * a];
        dst[0] = f2bf(rowv[0].f[c]); dst[1] = f2bf(rowv[1].f[c]);
        dst[2] = f2bf(rowv[2].f[c]); dst[3] = f2bf(rowv[3].f[c]);
      }
    }
    #pragma unroll
    for (int i = 0; i < 7; ++i) {
      int idx = i * 256 + t;
      int r = idx >> 4, c4 = (idx & 15) * 4;
      int n = n0 + c4;
      F4 mv; mv.v = make_float4(0.f, 0.f, 0.f, 0.f);
      if (r < PP) {
        if (n + 3 < NN) {
          mv.v = *(const float4*)&mask[((size_t)(b * PP + r)) * NN + n];
        } else {
          #pragma unroll
          for (int j = 0; j < 4; ++j)
            mv.f[j] = (n + j < NN) ? mask[((size_t)(b * PP + r)) * NN + n + j] : -1e30f;
        }
      }
      *(float4*)&PM[r][c4] = mv.v;
    }
    __syncthreads();

    float rsv[2][4];
    #pragma unroll
    for (int u = 0; u < 2; ++u) {
      int tt = w + 4 * u;
      if (tt >= 7) continue;
      f32x4 sa[4];
      #pragma unroll
      for (int nb = 0; nb < 4; ++nb) { sa[nb][0] = 0.f; sa[nb][1] = 0.f; sa[nb][2] = 0.f; sa[nb][3] = 0.f; }
      #pragma unroll
      for (int kb = 0; kb < 2; ++kb)
        #pragma unroll
        for (int nb = 0; nb < 4; ++nb) {
          bf16x8 kf = *(bf16x8*)&Kl[nb * 16 + lr][kb * 32 + lg * 8];
          sa[nb] = __builtin_amdgcn_mfma_f32_16x16x32_bf16(qf[u][kb], kf, sa[nb], 0, 0, 0);
        }
      #pragma unroll
      for (int j = 0; j < 4; ++j) {
        int pl = tt * 16 + lg * 4 + j;
        float s0 = sa[0][j] + PM[pl][lr];
        float s1 = sa[1][j] + PM[pl][16 + lr];
        float s2 = sa[2][j] + PM[pl][32 + lr];
        float s3 = sa[3][j] + PM[pl][48 + lr];
        float cm = fmaxf(fmaxf(s0, s1), fmaxf(s2, s3));
        #pragma unroll
        for (int off = 1; off < 16; off <<= 1) cm = fmaxf(cm, __shfl_xor(cm, off));
        float Mn = fmaxf(Mx[u][j], cm);
        float r = __expf(Mx[u][j] - Mn);
        float e0 = __expf(s0 - Mn), e1 = __expf(s1 - Mn);
        float e2 = __expf(s2 - Mn), e3 = __expf(s3 - Mn);
        float sum = (e0 + e1) + (e2 + e3);
        #pragma unroll
        for (int off = 1; off < 16; off <<= 1) sum += __shfl_xor(sum, off);
        Lx[u][j] = Lx[u][j] * r + sum;
        Mx[u][j] = Mn;
        rsv[u][j] = r;
        PM[pl][lr] = e0; PM[pl][16 + lr] = e1; PM[pl][32 + lr] = e2; PM[pl][48 + lr] = e3;
      }
    }
    __syncthreads();

    #pragma unroll
    for (int u = 0; u < 2; ++u) {
      int tt = w + 4 * u;
      if (tt >= 7) continue;
      #pragma unroll
      for (int dt = 0; dt < 4; ++dt) {
        f32x4 o = Oa[u][dt];
        o[0] *= rsv[u][0]; o[1] *= rsv[u][1]; o[2] *= rsv[u][2]; o[3] *= rsv[u][3];
        Oa[u][dt] = o;
      }
      #pragma unroll
      for (int kb = 0; kb < 2; ++kb) {
        F4 p0, p1;
        p0.v = *(const float4*)&PM[tt * 16 + lr][kb * 32 + lg * 8];
        p1.v = *(const float4*)&PM[tt * 16 + lr][kb * 32 + lg * 8 + 4];
        bf16x8 pf;
        #pragma unroll
        for (int i = 0; i < 4; ++i) { pf[i] = (short)f2bf(p0.f[i]); pf[i + 4] = (short)f2bf(p1.f[i]); }
        #pragma unroll
        for (int dt = 0; dt < 4; ++dt) {
          bf16x8 vf = *(bf16x8*)&Vt[dt * 16 + lr][kb * 32 + lg * 8];
          Oa[u][dt] = __builtin_amdgcn_mfma_f32_16x16x32_bf16(pf, vf, Oa[u][dt], 0, 0, 0);
        }
      }
    }
    __syncthreads();
  }

  #pragma unroll
  for (int u = 0; u < 2; ++u) {
    int tt = w + 4 * u;
    if (tt >= 7) continue;
    #pragma unroll
    for (int j = 0; j < 4; ++j) {
      int p = tt * 16 + lg * 4 + j;
      if (p >= PP) continue;
      float L = Lx[u][j];
      float inv = (L > 0.f) ? 1.0f / L : 0.f;
      #pragma unroll
      for (int dt = 0; dt < 4; ++dt)
        attn_out[((size_t)(b * PP + p)) * 512 + h * 64 + dt * 16 + lr] = Oa[u][dt][j] * inv;
    }
  }
}

// ---------------------------------------------------------------- K3: mh = attn_out @ mh_w^T + mh_b  (MFMA bf16)
__global__ __launch_bounds__(256) void k_mhgemm(
    const float* __restrict__ A, const float* __restrict__ W,
    const float* __restrict__ bias, float* __restrict__ out) {
  __shared__ unsigned short Xs[64][40];
  __shared__ unsigned short Ws[64][40];
  const int t = threadIdx.x;
  const int lane = t & 63;
  const int w = t >> 6;
  const int lr = lane & 15, lg = lane >> 4;
  const int rowBase = blockIdx.y * 64, colBase = blockIdx.x * 64;

  f32x4 acc[4];
  #pragma unroll
  for (int m = 0; m < 4; ++m) { acc[m][0] = 0.f; acc[m][1] = 0.f; acc[m][2] = 0.f; acc[m][3] = 0.f; }

  for (int kt = 0; kt < 16; ++kt) {
    const int koff = kt * 32;
    __syncthreads();
    #pragma unroll
    for (int i = 0; i < 2; ++i) {
      int s = i * 256 + t;
      int r = s >> 3, c4 = (s & 7) * 4;
      F4 xv, wv;
      xv.v = *(const float4*)&A[(size_t)(rowBase + r) * 512 + koff + c4];
      wv.v = *(const float4*)&W[(size_t)(colBase + r) * 512 + koff + c4];
      unsigned short* xd = &Xs[r][c4];
      unsigned short* wd = &Ws[r][c4];
      xd[0] = f2bf(xv.f[0]); xd[1] = f2bf(xv.f[1]); xd[2] = f2bf(xv.f[2]); xd[3] = f2bf(xv.f[3]);
      wd[0] = f2bf(wv.f[0]); wd[1] = f2bf(wv.f[1]); wd[2] = f2bf(wv.f[2]); wd[3] = f2bf(wv.f[3]);
    }
    __syncthreads();
    bf16x8 bfr = *(bf16x8*)&Ws[w * 16 + lr][lg * 8];
    #pragma unroll
    for (int m = 0; m < 4; ++m) {
      bf16x8 af = *(bf16x8*)&Xs[m * 16 + lr][lg * 8];
      acc[m] = __builtin_amdgcn_mfma_f32_16x16x32_bf16(af, bfr, acc[m], 0, 0, 0);
    }
  }

  const int o = colBase + w * 16 + lr;
  const float bv = bias[o];
  #pragma unroll
  for (int m = 0; m < 4; ++m) {
    #pragma unroll
    for (int j = 0; j < 4; ++j) {
      int row = rowBase + m * 16 + lg * 4 + j;
      out[(size_t)row * 512 + o] = acc[m][j] + bv;
    }
  }
}

// ---------------------------------------------------------------- K4a: score2 = mh @ shk (MFMA bf16), then 10*tanh(s/sqrtE - a*cd/cdmax) + mask
// Block = (n-chunk 64, batch). M = 100 padded to 112 (7 m-tiles), K = 512.
// Wave w owns n-tile w; each wave computes all 7 m-tiles.
// shk is [E][N] per batch -> staged transposed (attn Vt trick) into Bt[n][k].
__global__ __launch_bounds__(256) void k_final_score(
    const float* __restrict__ mh, const float* __restrict__ shk,
    const float* __restrict__ cur_dist, const float* __restrict__ rmax,
    const float* __restrict__ mask, const float* __restrict__ dist_alpha,
    float* __restrict__ sc_out) {
  __shared__ unsigned short As[112][40];
  __shared__ unsigned short Bt[64][40];
  const int t = threadIdx.x;
  const int lane = t & 63;
  const int w = t >> 6;
  const int lr = lane & 15, lg = lane >> 4;
  const int n0 = blockIdx.x * 64, b = blockIdx.y;

  f32x4 acc[7];
  #pragma unroll
  for (int m = 0; m < 7; ++m) { acc[m][0] = 0.f; acc[m][1] = 0.f; acc[m][2] = 0.f; acc[m][3] = 0.f; }

  for (int kt = 0; kt < 16; ++kt) {
    const int k0 = kt * 32;
    __syncthreads();
    // stage A chunk [112][32] (pad rows >= 100 with 0)
    #pragma unroll
    for (int i = 0; i < 4; ++i) {
      int s = i * 256 + t;                 // need 896 slots
      if (s < 896) {
        int r = s >> 3, c4 = (s & 7) * 4;
        F4 xv; xv.v = make_float4(0.f, 0.f, 0.f, 0.f);
        if (r < PP) xv.v = *(const float4*)&mh[(size_t)(b * PP + r) * 512 + k0 + c4];
        unsigned short* xd = &As[r][c4];
        xd[0] = f2bf(xv.f[0]); xd[1] = f2bf(xv.f[1]); xd[2] = f2bf(xv.f[2]); xd[3] = f2bf(xv.f[3]);
      }
    }
    // stage B transposed: Bt[n - n0][k - k0] from shk[b][k][n]
    if (t < 128) {
      int a = t & 15, kb = t >> 4;         // a: n-block (4), kb: k-block (4 rows)
      F4 rowv[4];
      #pragma unroll
      for (int r = 0; r < 4; ++r) {
        int k = k0 + 4 * kb + r;
        int n = n0 + 4 * a;
        rowv[r].v = (n < NN) ? *(const float4*)&shk[((size_t)b * EE + k) * NN + n]
                             : make_float4(0.f, 0.f, 0.f, 0.f);
      }
      #pragma unroll
      for (int c = 0; c < 4; ++c) {
        unsigned short* dst = &Bt[4 * a + c][4 * kb];
        dst[0] = f2bf(rowv[0].f[c]); dst[1] = f2bf(rowv[1].f[c]);
        dst[2] = f2bf(rowv[2].f[c]); dst[3] = f2bf(rowv[3].f[c]);
      }
    }
    __syncthreads();
    bf16x8 bfr = *(bf16x8*)&Bt[w * 16 + lr][lg * 8];
    #pragma unroll
    for (int m = 0; m < 7; ++m) {
      bf16x8 af = *(bf16x8*)&As[m * 16 + lr][lg * 8];
      acc[m] = __builtin_amdgcn_mfma_f32_16x16x32_bf16(af, bfr, acc[m], 0, 0, 0);
    }
  }

  const float alpha = dist_alpha[0];
  const int n = n0 + w * 16 + lr;
  if (n < NN) {
    #pragma unroll
    for (int m = 0; m < 7; ++m) {
      #pragma unroll
      for (int j = 0; j < 4; ++j) {
        int p = m * 16 + lg * 4 + j;
        if (p >= PP) continue;
        size_t rb = (size_t)(b * PP + p) * NN;
        float rmx = rmax[b * PP + p];
        float cd = cur_dist[rb + n];
        float mk = mask[rb + n];
        sc_out[rb + n] = CLIPV * fast_tanh(acc[m][j] * INVSQE - alpha * cd / rmx) + mk;
      }
    }
  }
}

// ---------------------------------------------------------------- K4b: row softmax over N
__global__ __launch_bounds__(256) void k_softmax(const float* __restrict__ sc,
                                                 float* __restrict__ out) {
  __shared__ float redm[4];
  __shared__ float redsum[4];
  const int row = blockIdx.x;
  const int t = threadIdx.x;
  const float* src = sc + (size_t)row * NN;
  float v0[4];
  float m = -1e30f;
  #pragma unroll
  for (int i = 0; i < 4; ++i) {
    int n = i * 256 + t;
    v0[i] = (n < NN) ? src[n] : -1e30f;
    m = fmaxf(m, v0[i]);
  }
  #pragma unroll
  for (int off = 32; off; off >>= 1) m = fmaxf(m, __shfl_xor(m, off));
  int wid = t >> 6, lane = t & 63;
  if (lane == 0) redm[wid] = m;
  __syncthreads();
  m = fmaxf(fmaxf(redm[0], redm[1]), fmaxf(redm[2], redm[3]));
  float e[4];
  float s = 0.f;
  #pragma unroll
  for (int i = 0; i < 4; ++i) {
    int n = i * 256 + t;
    e[i] = (n < NN) ? __expf(v0[i] - m) : 0.f;
    s += e[i];
  }
  #pragma unroll
  for (int off = 32; off; off >>= 1) s += __shfl_xor(s, off);
  if (lane == 0) redsum[wid] = s;
  __syncthreads();
  s = redsum[0] + redsum[1] + redsum[2] + redsum[3];
  float inv = 1.0f / s;
  #pragma unroll
  for (int i = 0; i < 4; ++i) {
    int n = i * 256 + t;
    if (n < NN) out[(size_t)row * NN + n] = e[i] * inv;
  }
}

// ----------------------------------------------------------------
extern "C" void kernel_launch(void* const* d_in, const int* in_sizes, int n_in,
                              void* d_out, int out_size, void* d_ws, size_t ws_size,
                              hipStream_t stream) {
  const float* eln       = (const float*)d_in[0];
  const float* ela       = (const float*)d_in[1];
  const float* cur_dist  = (const float*)d_in[2];
  const float* ninf      = (const float*)d_in[3];
  const float* lengths   = (const float*)d_in[4];
  const float* max_dis   = (const float*)d_in[5];
  const float* remain    = (const float*)d_in[6];
  const float* q_first   = (const float*)d_in[7];
  const float* kten      = (const float*)d_in[8];
  const float* vten      = (const float*)d_in[9];
  const float* shk       = (const float*)d_in[10];
  const float* Wq        = (const float*)d_in[11];
  const float* dis_emb   = (const float*)d_in[12];
  const float* mh_w      = (const float*)d_in[13];
  const float* mh_b      = (const float*)d_in[14];
  const float* dalpha    = (const float*)d_in[15];
  const int*   depot     = (const int*)d_in[16];
  const int*   route_cnt = (const int*)d_in[17];
  const int*   left_city = (const int*)d_in[18];
  const int*   city_num  = (const int*)d_in[19];
  float* out = (float*)d_out;

  float* ws      = (float*)d_ws;
  float* q_ws    = ws;                                   // 6400*512
  float* attn_ws = q_ws + (size_t)ROWS * 512;            // 6400*512
  float* mh_ws   = attn_ws + (size_t)ROWS * 512;         // 6400*512
  float* sc_ws   = mh_ws + (size_t)ROWS * 512;           // 6400*1000
  float* rmax_ws = sc_ws + (size_t)ROWS * NN;            // 6400

  k_rowmax<<<ROWS / 4, 256, 0, stream>>>(cur_dist, rmax_ws);
  k_qgemm<<<dim3(8, 100), 256, 0, stream>>>(eln, ela, lengths, max_dis, remain,
                                            q_first, Wq, dis_emb, depot, route_cnt,
                                            left_city, city_num, q_ws);
  k_attn<<<BB * HH, 256, 0, stream>>>(q_ws, kten, vten, ninf, attn_ws);
  k_mhgemm<<<dim3(8, 100), 256, 0, stream>>>(attn_ws, mh_w, mh_b, mh_ws);
  k_final_score<<<dim3(16, 64), 256, 0, stream>>>(mh_ws, shk, cur_dist, rmax_ws,
                                                  ninf, dalpha, sc_ws);
  k_softmax<<<ROWS, 256, 0, stream>>>(sc_ws, out);
}